// Round 5
// baseline (3227.752 us; speedup 1.0000x reference)
//
#include <hip/hip_runtime.h>
#include <math.h>

// Problem constants
#define B 64
#define NN 49
#define ENC 2048
#define DEC 512
#define ATT 512
#define EMB 300
#define VOC 10000
#define TT 30
#define NBLK 256

typedef __attribute__((ext_vector_type(4))) float f32x4;
typedef __attribute__((ext_vector_type(4))) short s16x4;
typedef __attribute__((ext_vector_type(8))) short s16x8;

__device__ __forceinline__ float fast_tanh(float x) {
    float e = __expf(2.f * x);
    return 1.f - 2.f / (e + 1.f);
}
__device__ __forceinline__ float sigmoidf(float x) {
    return 1.f / (1.f + __expf(-x));
}

// round-to-nearest-even f32 -> bf16 bits
__device__ __forceinline__ unsigned short f2bf(float x) {
    unsigned u = __float_as_uint(x);
    unsigned r = u + 0x7FFFu + ((u >> 16) & 1u);
    return (unsigned short)(r >> 16);
}
__device__ __forceinline__ void split_bf16(float x, short& hi, short& lo) {
    unsigned short h = f2bf(x);
    float hf = __uint_as_float((unsigned)h << 16);
    hi = (short)h;
    lo = (short)f2bf(x - hf);
}
__device__ __forceinline__ s16x8 ld8(const short* p) {
    s16x4 a = *(const s16x4*)p;
    s16x4 b = *(const s16x4*)(p + 4);
    return __builtin_shufflevector(a, b, 0, 1, 2, 3, 4, 5, 6, 7);
}

// ---------------------------------------------------------------------------
// Split-bf16 MFMA NT GEMM: C[M,N] = A[M,K] @ B[N,K]^T (+bias), ~f32 accuracy
// via (Ah+Al)(Bh+Bl) ~= AhBh + AhBl + AlBh.  128x128 tile, 8 waves, 16x16x32.
// mode 0: C[r*ldc+col]. mode 1: preds scatter (r = t*64+b -> [b][t][col]).
// ---------------------------------------------------------------------------
__global__ __launch_bounds__(512) void mfma_nt(
    const float* __restrict__ A, int lda,
    const float* __restrict__ Bm, int ldb,
    const float* __restrict__ bias,
    float* __restrict__ C, int ldc,
    int M, int N, int K, int mode)
{
    __shared__ short Ah[128][40];
    __shared__ short Al[128][40];
    __shared__ short Bh[128][40];
    __shared__ short Bl[128][40];

    const int tid = threadIdx.x;
    const int m0 = blockIdx.y * 128, n0 = blockIdx.x * 128;
    const int wid = tid >> 6, lane = tid & 63;
    const int wm = wid >> 2, wn = wid & 3;        // waves 2 (M) x 4 (N)
    const int lrow = lane & 15;
    const int lko = (lane >> 4) * 8;              // k-offset within 32

    const int srow = tid >> 2;                    // 0..127 staging row
    const int sk = (tid & 3) * 8;                 // 0,8,16,24

    f32x4 acc[4][2];
    #pragma unroll
    for (int i = 0; i < 4; ++i)
        #pragma unroll
        for (int j = 0; j < 2; ++j)
            acc[i][j] = (f32x4){0.f, 0.f, 0.f, 0.f};

    const int nkt = (K + 31) >> 5;
    for (int kt = 0; kt < nkt; ++kt) {
        const int kb0 = kt * 32 + sk;
        // ---- stage A ----
        {
            const int gr = m0 + srow;
            float v[8];
            if (gr < M && kb0 + 7 < K) {
                const float* p = A + (size_t)gr * lda + kb0;
                float4 x0 = *(const float4*)p;
                float4 x1 = *(const float4*)(p + 4);
                v[0] = x0.x; v[1] = x0.y; v[2] = x0.z; v[3] = x0.w;
                v[4] = x1.x; v[5] = x1.y; v[6] = x1.z; v[7] = x1.w;
            } else {
                #pragma unroll
                for (int j = 0; j < 8; ++j)
                    v[j] = (gr < M && kb0 + j < K) ? A[(size_t)gr * lda + kb0 + j] : 0.f;
            }
            s16x4 h0, h1, l0, l1;
            #pragma unroll
            for (int j = 0; j < 4; ++j) { short h, l; split_bf16(v[j], h, l); h0[j] = h; l0[j] = l; }
            #pragma unroll
            for (int j = 0; j < 4; ++j) { short h, l; split_bf16(v[4 + j], h, l); h1[j] = h; l1[j] = l; }
            *(s16x4*)&Ah[srow][sk] = h0; *(s16x4*)&Ah[srow][sk + 4] = h1;
            *(s16x4*)&Al[srow][sk] = l0; *(s16x4*)&Al[srow][sk + 4] = l1;
        }
        // ---- stage B ----
        {
            const int gc = n0 + srow;
            float v[8];
            if (gc < N && kb0 + 7 < K) {
                const float* p = Bm + (size_t)gc * ldb + kb0;
                float4 x0 = *(const float4*)p;
                float4 x1 = *(const float4*)(p + 4);
                v[0] = x0.x; v[1] = x0.y; v[2] = x0.z; v[3] = x0.w;
                v[4] = x1.x; v[5] = x1.y; v[6] = x1.z; v[7] = x1.w;
            } else {
                #pragma unroll
                for (int j = 0; j < 8; ++j)
                    v[j] = (gc < N && kb0 + j < K) ? Bm[(size_t)gc * ldb + kb0 + j] : 0.f;
            }
            s16x4 h0, h1, l0, l1;
            #pragma unroll
            for (int j = 0; j < 4; ++j) { short h, l; split_bf16(v[j], h, l); h0[j] = h; l0[j] = l; }
            #pragma unroll
            for (int j = 0; j < 4; ++j) { short h, l; split_bf16(v[4 + j], h, l); h1[j] = h; l1[j] = l; }
            *(s16x4*)&Bh[srow][sk] = h0; *(s16x4*)&Bh[srow][sk + 4] = h1;
            *(s16x4*)&Bl[srow][sk] = l0; *(s16x4*)&Bl[srow][sk + 4] = l1;
        }
        __syncthreads();

        s16x8 bh[2], bl[2];
        #pragma unroll
        for (int nr = 0; nr < 2; ++nr) {
            const int col = wn * 32 + nr * 16 + lrow;
            bh[nr] = ld8(&Bh[col][lko]);
            bl[nr] = ld8(&Bl[col][lko]);
        }
        #pragma unroll
        for (int mr = 0; mr < 4; ++mr) {
            const int row = wm * 64 + mr * 16 + lrow;
            s16x8 ah = ld8(&Ah[row][lko]);
            s16x8 al = ld8(&Al[row][lko]);
            #pragma unroll
            for (int nr = 0; nr < 2; ++nr) {
                acc[mr][nr] = __builtin_amdgcn_mfma_f32_16x16x32_bf16(ah, bh[nr], acc[mr][nr], 0, 0, 0);
                acc[mr][nr] = __builtin_amdgcn_mfma_f32_16x16x32_bf16(ah, bl[nr], acc[mr][nr], 0, 0, 0);
                acc[mr][nr] = __builtin_amdgcn_mfma_f32_16x16x32_bf16(al, bh[nr], acc[mr][nr], 0, 0, 0);
            }
        }
        __syncthreads();
    }

    // epilogue: D layout col=lane&15, row=(lane>>4)*4+reg
    #pragma unroll
    for (int mr = 0; mr < 4; ++mr) {
        #pragma unroll
        for (int nr = 0; nr < 2; ++nr) {
            #pragma unroll
            for (int r = 0; r < 4; ++r) {
                const int row = m0 + wm * 64 + mr * 16 + (lane >> 4) * 4 + r;
                const int col = n0 + wn * 32 + nr * 16 + (lane & 15);
                if (row < M && col < N) {
                    float val = acc[mr][nr][r] + (bias ? bias[col] : 0.f);
                    if (mode == 0) C[(size_t)row * ldc + col] = val;
                    else {
                        const int t = row >> 6, bb = row & 63;
                        C[(size_t)bb * (TT * VOC) + (size_t)t * VOC + col] = val;
                    }
                }
            }
        }
    }
}

__global__ __launch_bounds__(256) void k_mean(const float* __restrict__ f,
                                              float* __restrict__ mean_f)
{
    const int b = blockIdx.x;
    for (int e = threadIdx.x; e < ENC; e += 256) {
        float s = 0.f;
        for (int n = 0; n < NN; ++n) s += f[(size_t)(b * NN + n) * ENC + e];
        mean_f[(size_t)b * ENC + e] = s * (1.f / 49.f);
    }
}

// ---------------------------------------------------------------------------
// init h0/c0, split-K: grid (16 colblocks of 64 in [0,1024), 16 kslices of 128)
// ---------------------------------------------------------------------------
__global__ __launch_bounds__(256) void k_init_partial(
    const float* __restrict__ mean_f,
    const float* __restrict__ iH_w, const float* __restrict__ iC_w,
    float* __restrict__ pbuf)
{
    const int tid = threadIdx.x;
    const int tx = tid & 15, ty = tid >> 4;
    const int n0 = blockIdx.x * 64;
    const int ks = blockIdx.y;
    __shared__ float As[16][64];
    __shared__ float Bs[16][64];
    float acc[4][4] = {};
    const int lrow = tid >> 2;
    const int lk = (tid & 3) * 4;
    for (int c = 0; c < 8; ++c) {
        const int kk = ks * 128 + c * 16 + lk;
        float4 av = *(const float4*)(mean_f + (size_t)lrow * 2048 + kk);
        const int col = n0 + lrow;
        const float* wp = (col < 512) ? (iH_w + (size_t)col * 2048)
                                      : (iC_w + (size_t)(col - 512) * 2048);
        float4 bv = *(const float4*)(wp + kk);
        As[lk + 0][lrow] = av.x; As[lk + 1][lrow] = av.y;
        As[lk + 2][lrow] = av.z; As[lk + 3][lrow] = av.w;
        Bs[lk + 0][lrow] = bv.x; Bs[lk + 1][lrow] = bv.y;
        Bs[lk + 2][lrow] = bv.z; Bs[lk + 3][lrow] = bv.w;
        __syncthreads();
        #pragma unroll
        for (int k = 0; k < 16; ++k) {
            float4 a = *(const float4*)&As[k][ty * 4];
            float4 b = *(const float4*)&Bs[k][tx * 4];
            acc[0][0] += a.x * b.x; acc[0][1] += a.x * b.y; acc[0][2] += a.x * b.z; acc[0][3] += a.x * b.w;
            acc[1][0] += a.y * b.x; acc[1][1] += a.y * b.y; acc[1][2] += a.y * b.z; acc[1][3] += a.y * b.w;
            acc[2][0] += a.z * b.x; acc[2][1] += a.z * b.y; acc[2][2] += a.z * b.z; acc[2][3] += a.z * b.w;
            acc[3][0] += a.w * b.x; acc[3][1] += a.w * b.y; acc[3][2] += a.w * b.z; acc[3][3] += a.w * b.w;
        }
        __syncthreads();
    }
    #pragma unroll
    for (int i = 0; i < 4; ++i) {
        const int r = ty * 4 + i;
        #pragma unroll
        for (int j = 0; j < 4; ++j)
            pbuf[(size_t)(ks * 64 + r) * 1024 + n0 + tx * 4 + j] = acc[i][j];
    }
}

__global__ __launch_bounds__(256) void k_init_reduce(
    const float* __restrict__ pbuf,
    const float* __restrict__ iH_b, const float* __restrict__ iC_b,
    float* __restrict__ h_cur, float* __restrict__ c_cur)
{
    const int idx = blockIdx.x * 256 + threadIdx.x;   // 0..65535
    const int r = idx >> 10, c = idx & 1023;
    float s = 0.f;
    #pragma unroll
    for (int ks = 0; ks < 16; ++ks) s += pbuf[(size_t)(ks * 64 + r) * 1024 + c];
    if (c < 512) h_cur[r * 512 + c] = s + iH_b[c];
    else         c_cur[r * 512 + (c - 512)] = s + iC_b[c - 512];
}

__global__ __launch_bounds__(256) void k_embed(const int* __restrict__ cap,
                                               const float* __restrict__ emb,
                                               float* __restrict__ embeds)
{
    const int r = blockIdx.x;
    const int t = r >> 6, b = r & 63;
    const int c = cap[b * 31 + t];
    for (int j = threadIdx.x; j < EMB; j += 256)
        embeds[(size_t)r * EMB + j] = emb[(size_t)c * EMB + j];
}

__global__ void k_bias2(const float* __restrict__ a, const float* __restrict__ b,
                        float* __restrict__ o)
{
    const int j = blockIdx.x * 256 + threadIdx.x;
    if (j < 2048) o[j] = a[j] + b[j];
}

__global__ void k_zero(unsigned* __restrict__ p) { p[0] = 0u; p[1] = 0u; }

// ---------------------------------------------------------------------------
// Persistent recurrence kernel: all 30 steps, 2 grid barriers per step.
// grid = 256 blocks x 512 threads; LDS 66.6 KB -> <=2 blocks/CU, so all 256
// blocks are co-resident on 256 CUs (deadlock-free spin barrier).
// ---------------------------------------------------------------------------
struct SMemBC {
    float wah[512];
    float awl[512];
    float red[64];
    float al[64];
    float gl[4][128];
};
union SMemU {
    float h[64][260];   // phase A: h staged f32, padded row stride 260
    SMemBC bc;
};

__device__ __forceinline__ void gbar(unsigned* cnt, unsigned target) {
    __syncthreads();
    if (threadIdx.x == 0) {
        __threadfence();  // release: make this block's writes agent-visible
        __hip_atomic_fetch_add(cnt, 1u, __ATOMIC_RELEASE, __HIP_MEMORY_SCOPE_AGENT);
        while (__hip_atomic_load(cnt, __ATOMIC_ACQUIRE, __HIP_MEMORY_SCOPE_AGENT) < target)
            __builtin_amdgcn_s_sleep(1);
        __threadfence();  // acquire: invalidate stale cached data
    }
    __syncthreads();
}

__global__ __launch_bounds__(512) void k_recur(
    const float* __restrict__ W_w, const float* __restrict__ W_b,
    const float* __restrict__ hh_w,
    const float* __restrict__ A_w, const float* __restrict__ A_b,
    const float* __restrict__ u_hs, const float* __restrict__ pre_x,
    const float* __restrict__ fW,
    float* __restrict__ h_cur, float* __restrict__ c_cur,
    float* __restrict__ wahT, float* __restrict__ ghhT,
    float* __restrict__ Hall, float* __restrict__ alphas,
    unsigned* __restrict__ cnt)
{
    __shared__ SMemU sm;
    const int g = blockIdx.x;
    const int tid = threadIdx.x;
    const int lane = tid & 63;
    const int w = tid >> 6;
    const int bb = g & 63;           // phase BC: batch element
    const int qq = g >> 6;           // phase BC: d-quadrant (0..3)
    unsigned tgt = 0;

    for (int s = 0; s < TT; ++s) {
        // ================= phase A: wah/ghh = h @ [W_w ; hh_w]^T (f32) ======
        {
            const int base = g * 10;
            const int C0 = base + w;                       // cols 0..7 of block
            const int C1 = (w < 2) ? (base + 8 + w) : -1;  // cols 8,9
            float acc0 = 0.f, acc1 = 0.f;
            for (int kh = 0; kh < 2; ++kh) {
                __syncthreads();
                // stage h[:, kh*256 .. +256) -> LDS (coalesced)
                {
                    const int b = tid >> 3;
                    const int k0 = (tid & 7) * 32;
                    const float* src = h_cur + b * 512 + kh * 256 + k0;
                    #pragma unroll
                    for (int i = 0; i < 8; ++i)
                        *(f32x4*)&sm.h[b][k0 + i * 4] = *(const f32x4*)(src + i * 4);
                }
                __syncthreads();
                {
                    const int C0u = __builtin_amdgcn_readfirstlane(C0);
                    const float* wr = ((C0u < 512) ? (W_w + (size_t)C0u * 512)
                                                   : (hh_w + (size_t)(C0u - 512) * 512)) + kh * 256;
                    #pragma unroll 4
                    for (int k = 0; k < 256; k += 4) {
                        f32x4 wv = *(const f32x4*)(wr + k);
                        f32x4 hv = *(const f32x4*)&sm.h[lane][k];
                        acc0 += wv[0] * hv[0] + wv[1] * hv[1] + wv[2] * hv[2] + wv[3] * hv[3];
                    }
                    if (C1 >= 0) {
                        const int C1u = __builtin_amdgcn_readfirstlane(C1);
                        const float* wr1 = ((C1u < 512) ? (W_w + (size_t)C1u * 512)
                                                        : (hh_w + (size_t)(C1u - 512) * 512)) + kh * 256;
                        #pragma unroll 4
                        for (int k = 0; k < 256; k += 4) {
                            f32x4 wv = *(const f32x4*)(wr1 + k);
                            f32x4 hv = *(const f32x4*)&sm.h[lane][k];
                            acc1 += wv[0] * hv[0] + wv[1] * hv[1] + wv[2] * hv[2] + wv[3] * hv[3];
                        }
                    }
                }
            }
            // transposed stores (coalesced: 64 consecutive floats per col)
            if (C0 < 512) wahT[C0 * 64 + lane] = acc0 + W_b[C0];
            else          ghhT[(C0 - 512) * 64 + lane] = acc0;
            if (C1 >= 0) {
                if (C1 < 512) wahT[C1 * 64 + lane] = acc1 + W_b[C1];
                else          ghhT[(C1 - 512) * 64 + lane] = acc1;
            }
        }
        tgt += NBLK; gbar(cnt, tgt);

        // ================= phase BC: scores+softmax+gates+LSTM ==============
        {
            sm.bc.wah[tid] = wahT[tid * 64 + bb];
            sm.bc.awl[tid] = A_w[tid];
            __syncthreads();

            // scores (redundant across the 4 q-blocks of bb; same-XCD L2 dedup)
            for (int n = w; n < NN; n += 8) {
                const float* up = u_hs + (size_t)(bb * NN + n) * 512;
                float acc = 0.f;
                #pragma unroll
                for (int i = 0; i < 8; ++i) {
                    const int a = lane + i * 64;
                    acc += sm.bc.awl[a] * fast_tanh(up[a] + sm.bc.wah[a]);
                }
                #pragma unroll
                for (int m = 32; m; m >>= 1) acc += __shfl_xor(acc, m, 64);
                if (lane == 0) sm.bc.red[n] = acc + A_b[0];
            }
            __syncthreads();

            if (tid < 64) {
                const float sc = (tid < NN) ? sm.bc.red[tid] : -1e30f;
                float mx = sc;
                #pragma unroll
                for (int m = 32; m; m >>= 1) mx = fmaxf(mx, __shfl_xor(mx, m, 64));
                float e = (tid < NN) ? __expf(sc - mx) : 0.f;
                float sum = e;
                #pragma unroll
                for (int m = 32; m; m >>= 1) sum += __shfl_xor(sum, m, 64);
                const float av = e / sum;
                sm.bc.al[tid] = av;
                if (qq == 0 && tid < NN)
                    alphas[(size_t)bb * (TT * NN) + (size_t)s * NN + tid] = av;
            }
            __syncthreads();

            // gates: thread = (gate, dloc); full 49-term alpha contraction
            const int gate = tid >> 7, dloc = tid & 127;
            const int j = gate * 512 + qq * 128 + dloc;
            float acc = pre_x[(size_t)(s * 64 + bb) * 2048 + j] + ghhT[j * 64 + bb];
            const float* fb = fW + (size_t)(bb * NN) * 2048 + j;
            #pragma unroll 7
            for (int n = 0; n < NN; ++n)
                acc += sm.bc.al[n] * fb[(size_t)n * 2048];
            sm.bc.gl[gate][dloc] = acc;
            __syncthreads();

            if (tid < 128) {
                const int dd = qq * 128 + tid;
                const float ig = sigmoidf(sm.bc.gl[0][tid]);
                const float fg = sigmoidf(sm.bc.gl[1][tid]);
                const float gg = fast_tanh(sm.bc.gl[2][tid]);
                const float og = sigmoidf(sm.bc.gl[3][tid]);
                const float cv = fg * c_cur[bb * 512 + dd] + ig * gg;
                const float hv = og * fast_tanh(cv);
                c_cur[bb * 512 + dd] = cv;
                h_cur[bb * 512 + dd] = hv;
                Hall[(size_t)(s * 64 + bb) * 512 + dd] = hv;
            }
        }
        tgt += NBLK; gbar(cnt, tgt);
    }
}

// ---------------------------------------------------------------------------
extern "C" void kernel_launch(void* const* d_in, const int* in_sizes, int n_in,
                              void* d_out, int out_size, void* d_ws, size_t ws_size,
                              hipStream_t stream)
{
    const float* features = (const float*)d_in[0];
    const int*   captions = (const int*)d_in[1];
    const float* emb      = (const float*)d_in[2];
    const float* U_w      = (const float*)d_in[3];
    const float* U_b      = (const float*)d_in[4];
    const float* W_w      = (const float*)d_in[5];
    const float* W_b      = (const float*)d_in[6];
    const float* A_w      = (const float*)d_in[7];
    const float* A_b      = (const float*)d_in[8];
    const float* iH_w     = (const float*)d_in[9];
    const float* iH_b     = (const float*)d_in[10];
    const float* iC_w     = (const float*)d_in[11];
    const float* iC_b     = (const float*)d_in[12];
    const float* ih_w     = (const float*)d_in[13];
    const float* ih_b     = (const float*)d_in[14];
    const float* hh_w     = (const float*)d_in[15];
    const float* hh_b     = (const float*)d_in[16];
    const float* fcn_w    = (const float*)d_in[17];
    const float* fcn_b    = (const float*)d_in[18];

    float* out    = (float*)d_out;
    float* alphas = out + (size_t)B * TT * VOC;

    float* ws     = (float*)d_ws;
    float* fW     = ws;                       // 3136*2048 = 6,422,528
    float* u_hs   = fW + 6422528;             // 3136*512  = 1,605,632
    float* pre_x  = u_hs + 1605632;           // 1920*2048 = 3,932,160
    float* Hall   = pre_x + 3932160;          // 1920*512  = 983,040
    float* mean_f = Hall + 983040;            // 131,072
    float* h_cur  = mean_f + 131072;          // 32,768
    float* c_cur  = h_cur + 32768;            // 32,768
    float* wahT   = c_cur + 32768;            // 512*64    = 32,768
    float* ghhT   = wahT + 32768;             // 2048*64   = 131,072
    float* embeds = ghhT + 131072;            // 1920*300  = 576,000
    float* bias2  = embeds + 576000;          // 2,048
    unsigned* cnt = (unsigned*)(bias2 + 2048);
    float* pbuf   = fW;                       // alias: init partials (dead before fW GEMM)

    // init hidden state (split-K, fully parallel)
    k_mean<<<64, 256, 0, stream>>>(features, mean_f);
    k_init_partial<<<dim3(16, 16), 256, 0, stream>>>(mean_f, iH_w, iC_w, pbuf);
    k_init_reduce<<<256, 256, 0, stream>>>(pbuf, iH_b, iC_b, h_cur, c_cur);

    // hoisted precomputes
    k_embed<<<1920, 256, 0, stream>>>(captions, emb, embeds);
    k_bias2<<<8, 256, 0, stream>>>(ih_b, hh_b, bias2);
    k_zero<<<1, 1, 0, stream>>>(cnt);
    // u_hs = features @ U_w^T + U_b                 [3136, 512]
    mfma_nt<<<dim3(4, 25), 512, 0, stream>>>(features, ENC, U_w, ENC, U_b, u_hs, ATT, B * NN, ATT, ENC, 0);
    // pre_x = embeds @ ih_w[:, :300]^T + (ih_b+hh_b) [1920, 2048]
    mfma_nt<<<dim3(16, 15), 512, 0, stream>>>(embeds, EMB, ih_w, 2348, bias2, pre_x, 2048, TT * B, 2048, EMB, 0);
    // fW = features @ ih_w[:, 300:2348]^T            [3136, 2048]
    mfma_nt<<<dim3(16, 25), 512, 0, stream>>>(features, ENC, ih_w + 300, 2348, nullptr, fW, 2048, B * NN, 2048, ENC, 0);

    // entire 30-step recurrence in one persistent kernel
    k_recur<<<NBLK, 512, 0, stream>>>(W_w, W_b, hh_w, A_w, A_b, u_hs, pre_x, fW,
                                      h_cur, c_cur, wahT, ghhT, Hall, alphas, cnt);

    // batched output projection
    mfma_nt<<<dim3(79, 15), 512, 0, stream>>>(Hall, DEC, fcn_w, DEC, fcn_b, out, VOC,
                                              TT * B, VOC, DEC, 1);
}

// Round 6
// 1112.712 us; speedup vs baseline: 2.9008x; 2.9008x over previous
//
#include <hip/hip_runtime.h>
#include <math.h>

// Problem constants
#define B 64
#define NN 49
#define ENC 2048
#define DEC 512
#define ATT 512
#define EMB 300
#define VOC 10000
#define TT 30

typedef __attribute__((ext_vector_type(4))) float f32x4;
typedef __attribute__((ext_vector_type(4))) short s16x4;
typedef __attribute__((ext_vector_type(8))) short s16x8;

__device__ __forceinline__ float fast_tanh(float x) {
    float e = __expf(2.f * x);
    return 1.f - 2.f / (e + 1.f);
}
__device__ __forceinline__ float sigmoidf(float x) {
    return 1.f / (1.f + __expf(-x));
}

// round-to-nearest-even f32 -> bf16 bits
__device__ __forceinline__ unsigned short f2bf(float x) {
    unsigned u = __float_as_uint(x);
    unsigned r = u + 0x7FFFu + ((u >> 16) & 1u);
    return (unsigned short)(r >> 16);
}
__device__ __forceinline__ void split_bf16(float x, short& hi, short& lo) {
    unsigned short h = f2bf(x);
    float hf = __uint_as_float((unsigned)h << 16);
    hi = (short)h;
    lo = (short)f2bf(x - hf);
}
__device__ __forceinline__ s16x8 ld8(const short* p) {
    s16x4 a = *(const s16x4*)p;
    s16x4 b = *(const s16x4*)(p + 4);
    return __builtin_shufflevector(a, b, 0, 1, 2, 3, 4, 5, 6, 7);
}

// ---------------------------------------------------------------------------
// Split-bf16 MFMA NT GEMM: C[M,N] = A[M,K] @ B[N,K]^T (+bias), ~f32 accuracy
// via (Ah+Al)(Bh+Bl) ~= AhBh + AhBl + AlBh.  128x128 tile, 8 waves, 16x16x32.
// mode 0: C[r*ldc+col]. mode 1: preds scatter (r = t*64+b -> [b][t][col]).
// ---------------------------------------------------------------------------
__global__ __launch_bounds__(512) void mfma_nt(
    const float* __restrict__ A, int lda,
    const float* __restrict__ Bm, int ldb,
    const float* __restrict__ bias,
    float* __restrict__ C, int ldc,
    int M, int N, int K, int mode)
{
    __shared__ short Ah[128][40];
    __shared__ short Al[128][40];
    __shared__ short Bh[128][40];
    __shared__ short Bl[128][40];

    const int tid = threadIdx.x;
    const int m0 = blockIdx.y * 128, n0 = blockIdx.x * 128;
    const int wid = tid >> 6, lane = tid & 63;
    const int wm = wid >> 2, wn = wid & 3;        // waves 2 (M) x 4 (N)
    const int lrow = lane & 15;
    const int lko = (lane >> 4) * 8;              // k-offset within 32

    const int srow = tid >> 2;                    // 0..127 staging row
    const int sk = (tid & 3) * 8;                 // 0,8,16,24

    f32x4 acc[4][2];
    #pragma unroll
    for (int i = 0; i < 4; ++i)
        #pragma unroll
        for (int j = 0; j < 2; ++j)
            acc[i][j] = (f32x4){0.f, 0.f, 0.f, 0.f};

    const int nkt = (K + 31) >> 5;
    for (int kt = 0; kt < nkt; ++kt) {
        const int kb0 = kt * 32 + sk;
        // ---- stage A ----
        {
            const int gr = m0 + srow;
            float v[8];
            if (gr < M && kb0 + 7 < K) {
                const float* p = A + (size_t)gr * lda + kb0;
                float4 x0 = *(const float4*)p;
                float4 x1 = *(const float4*)(p + 4);
                v[0] = x0.x; v[1] = x0.y; v[2] = x0.z; v[3] = x0.w;
                v[4] = x1.x; v[5] = x1.y; v[6] = x1.z; v[7] = x1.w;
            } else {
                #pragma unroll
                for (int j = 0; j < 8; ++j)
                    v[j] = (gr < M && kb0 + j < K) ? A[(size_t)gr * lda + kb0 + j] : 0.f;
            }
            s16x4 h0, h1, l0, l1;
            #pragma unroll
            for (int j = 0; j < 4; ++j) { short h, l; split_bf16(v[j], h, l); h0[j] = h; l0[j] = l; }
            #pragma unroll
            for (int j = 0; j < 4; ++j) { short h, l; split_bf16(v[4 + j], h, l); h1[j] = h; l1[j] = l; }
            *(s16x4*)&Ah[srow][sk] = h0; *(s16x4*)&Ah[srow][sk + 4] = h1;
            *(s16x4*)&Al[srow][sk] = l0; *(s16x4*)&Al[srow][sk + 4] = l1;
        }
        // ---- stage B ----
        {
            const int gc = n0 + srow;
            float v[8];
            if (gc < N && kb0 + 7 < K) {
                const float* p = Bm + (size_t)gc * ldb + kb0;
                float4 x0 = *(const float4*)p;
                float4 x1 = *(const float4*)(p + 4);
                v[0] = x0.x; v[1] = x0.y; v[2] = x0.z; v[3] = x0.w;
                v[4] = x1.x; v[5] = x1.y; v[6] = x1.z; v[7] = x1.w;
            } else {
                #pragma unroll
                for (int j = 0; j < 8; ++j)
                    v[j] = (gc < N && kb0 + j < K) ? Bm[(size_t)gc * ldb + kb0 + j] : 0.f;
            }
            s16x4 h0, h1, l0, l1;
            #pragma unroll
            for (int j = 0; j < 4; ++j) { short h, l; split_bf16(v[j], h, l); h0[j] = h; l0[j] = l; }
            #pragma unroll
            for (int j = 0; j < 4; ++j) { short h, l; split_bf16(v[4 + j], h, l); h1[j] = h; l1[j] = l; }
            *(s16x4*)&Bh[srow][sk] = h0; *(s16x4*)&Bh[srow][sk + 4] = h1;
            *(s16x4*)&Bl[srow][sk] = l0; *(s16x4*)&Bl[srow][sk + 4] = l1;
        }
        __syncthreads();

        s16x8 bh[2], bl[2];
        #pragma unroll
        for (int nr = 0; nr < 2; ++nr) {
            const int col = wn * 32 + nr * 16 + lrow;
            bh[nr] = ld8(&Bh[col][lko]);
            bl[nr] = ld8(&Bl[col][lko]);
        }
        #pragma unroll
        for (int mr = 0; mr < 4; ++mr) {
            const int row = wm * 64 + mr * 16 + lrow;
            s16x8 ah = ld8(&Ah[row][lko]);
            s16x8 al = ld8(&Al[row][lko]);
            #pragma unroll
            for (int nr = 0; nr < 2; ++nr) {
                acc[mr][nr] = __builtin_amdgcn_mfma_f32_16x16x32_bf16(ah, bh[nr], acc[mr][nr], 0, 0, 0);
                acc[mr][nr] = __builtin_amdgcn_mfma_f32_16x16x32_bf16(ah, bl[nr], acc[mr][nr], 0, 0, 0);
                acc[mr][nr] = __builtin_amdgcn_mfma_f32_16x16x32_bf16(al, bh[nr], acc[mr][nr], 0, 0, 0);
            }
        }
        __syncthreads();
    }

    // epilogue: D layout col=lane&15, row=(lane>>4)*4+reg
    #pragma unroll
    for (int mr = 0; mr < 4; ++mr) {
        #pragma unroll
        for (int nr = 0; nr < 2; ++nr) {
            #pragma unroll
            for (int r = 0; r < 4; ++r) {
                const int row = m0 + wm * 64 + mr * 16 + (lane >> 4) * 4 + r;
                const int col = n0 + wn * 32 + nr * 16 + (lane & 15);
                if (row < M && col < N) {
                    float val = acc[mr][nr][r] + (bias ? bias[col] : 0.f);
                    if (mode == 0) C[(size_t)row * ldc + col] = val;
                    else {
                        const int t = row >> 6, bb = row & 63;
                        C[(size_t)bb * (TT * VOC) + (size_t)t * VOC + col] = val;
                    }
                }
            }
        }
    }
}

__global__ __launch_bounds__(256) void k_mean(const float* __restrict__ f,
                                              float* __restrict__ mean_f)
{
    const int b = blockIdx.x;
    for (int e = threadIdx.x; e < ENC; e += 256) {
        float s = 0.f;
        for (int n = 0; n < NN; ++n) s += f[(size_t)(b * NN + n) * ENC + e];
        mean_f[(size_t)b * ENC + e] = s * (1.f / 49.f);
    }
}

// ---------------------------------------------------------------------------
// init h0/c0, split-K: grid (16 colblocks of 64 in [0,1024), 16 kslices of 128)
// ---------------------------------------------------------------------------
__global__ __launch_bounds__(256) void k_init_partial(
    const float* __restrict__ mean_f,
    const float* __restrict__ iH_w, const float* __restrict__ iC_w,
    float* __restrict__ pbuf)
{
    const int tid = threadIdx.x;
    const int tx = tid & 15, ty = tid >> 4;
    const int n0 = blockIdx.x * 64;
    const int ks = blockIdx.y;
    __shared__ float As[16][64];
    __shared__ float Bs[16][64];
    float acc[4][4] = {};
    const int lrow = tid >> 2;
    const int lk = (tid & 3) * 4;
    for (int c = 0; c < 8; ++c) {
        const int kk = ks * 128 + c * 16 + lk;
        float4 av = *(const float4*)(mean_f + (size_t)lrow * 2048 + kk);
        const int col = n0 + lrow;
        const float* wp = (col < 512) ? (iH_w + (size_t)col * 2048)
                                      : (iC_w + (size_t)(col - 512) * 2048);
        float4 bv = *(const float4*)(wp + kk);
        As[lk + 0][lrow] = av.x; As[lk + 1][lrow] = av.y;
        As[lk + 2][lrow] = av.z; As[lk + 3][lrow] = av.w;
        Bs[lk + 0][lrow] = bv.x; Bs[lk + 1][lrow] = bv.y;
        Bs[lk + 2][lrow] = bv.z; Bs[lk + 3][lrow] = bv.w;
        __syncthreads();
        #pragma unroll
        for (int k = 0; k < 16; ++k) {
            float4 a = *(const float4*)&As[k][ty * 4];
            float4 b = *(const float4*)&Bs[k][tx * 4];
            acc[0][0] += a.x * b.x; acc[0][1] += a.x * b.y; acc[0][2] += a.x * b.z; acc[0][3] += a.x * b.w;
            acc[1][0] += a.y * b.x; acc[1][1] += a.y * b.y; acc[1][2] += a.y * b.z; acc[1][3] += a.y * b.w;
            acc[2][0] += a.z * b.x; acc[2][1] += a.z * b.y; acc[2][2] += a.z * b.z; acc[2][3] += a.z * b.w;
            acc[3][0] += a.w * b.x; acc[3][1] += a.w * b.y; acc[3][2] += a.w * b.z; acc[3][3] += a.w * b.w;
        }
        __syncthreads();
    }
    #pragma unroll
    for (int i = 0; i < 4; ++i) {
        const int r = ty * 4 + i;
        #pragma unroll
        for (int j = 0; j < 4; ++j)
            pbuf[(size_t)(ks * 64 + r) * 1024 + n0 + tx * 4 + j] = acc[i][j];
    }
}

__global__ __launch_bounds__(256) void k_init_reduce(
    const float* __restrict__ pbuf,
    const float* __restrict__ iH_b, const float* __restrict__ iC_b,
    float* __restrict__ h_cur, float* __restrict__ c_cur)
{
    const int idx = blockIdx.x * 256 + threadIdx.x;   // 0..65535
    const int r = idx >> 10, c = idx & 1023;
    float s = 0.f;
    #pragma unroll
    for (int ks = 0; ks < 16; ++ks) s += pbuf[(size_t)(ks * 64 + r) * 1024 + c];
    if (c < 512) h_cur[r * 512 + c] = s + iH_b[c];
    else         c_cur[r * 512 + (c - 512)] = s + iC_b[c - 512];
}

__global__ __launch_bounds__(256) void k_embed(const int* __restrict__ cap,
                                               const float* __restrict__ emb,
                                               float* __restrict__ embeds)
{
    const int r = blockIdx.x;
    const int t = r >> 6, b = r & 63;
    const int c = cap[b * 31 + t];
    for (int j = threadIdx.x; j < EMB; j += 256)
        embeds[(size_t)r * EMB + j] = emb[(size_t)c * EMB + j];
}

__global__ void k_bias2(const float* __restrict__ a, const float* __restrict__ b,
                        float* __restrict__ o)
{
    const int j = blockIdx.x * 256 + threadIdx.x;
    if (j < 2048) o[j] = a[j] + b[j];
}

// ---------------------------------------------------------------------------
// wah/ghh split-K GEMM: grid (40, 4). y = h @ [W_w ; hh_w]^T over K-quarter.
// cols 0..511 -> wahp[ks][64][512] (+W_b at ks 0); else ghhp[ks][64][2048].
// ---------------------------------------------------------------------------
__global__ __launch_bounds__(256) void k_hw4(
    const float* __restrict__ h,
    const float* __restrict__ W_w, const float* __restrict__ W_b,
    const float* __restrict__ hh_w,
    float* __restrict__ wahp, float* __restrict__ ghhp)
{
    const int tid = threadIdx.x;
    const int tx = tid & 15, ty = tid >> 4;
    const int n0 = blockIdx.x * 64;
    const int ks = blockIdx.y;   // 0..3
    const float* Bp; const float* biasp; float* Cp; int c0, ldc;
    if (n0 < 512) { Bp = W_w + (size_t)n0 * 512; biasp = (ks == 0) ? W_b : nullptr; Cp = wahp + (size_t)ks * 32768; c0 = n0; ldc = 512; }
    else { Bp = hh_w + (size_t)(n0 - 512) * 512; biasp = nullptr; Cp = ghhp + (size_t)ks * 131072; c0 = n0 - 512; ldc = 2048; }

    __shared__ float As[16][64];
    __shared__ float Bs[16][64];
    float acc[4][4] = {};
    const int lrow = tid >> 2;
    const int lk = (tid & 3) * 4;
    for (int c = 0; c < 8; ++c) {
        const int kk = ks * 128 + c * 16 + lk;
        float4 av = *(const float4*)(h + (size_t)lrow * 512 + kk);
        float4 bv = *(const float4*)(Bp + (size_t)lrow * 512 + kk);
        As[lk + 0][lrow] = av.x; As[lk + 1][lrow] = av.y;
        As[lk + 2][lrow] = av.z; As[lk + 3][lrow] = av.w;
        Bs[lk + 0][lrow] = bv.x; Bs[lk + 1][lrow] = bv.y;
        Bs[lk + 2][lrow] = bv.z; Bs[lk + 3][lrow] = bv.w;
        __syncthreads();
        #pragma unroll
        for (int k = 0; k < 16; ++k) {
            float4 a = *(const float4*)&As[k][ty * 4];
            float4 b = *(const float4*)&Bs[k][tx * 4];
            acc[0][0] += a.x * b.x; acc[0][1] += a.x * b.y; acc[0][2] += a.x * b.z; acc[0][3] += a.x * b.w;
            acc[1][0] += a.y * b.x; acc[1][1] += a.y * b.y; acc[1][2] += a.y * b.z; acc[1][3] += a.y * b.w;
            acc[2][0] += a.z * b.x; acc[2][1] += a.z * b.y; acc[2][2] += a.z * b.z; acc[2][3] += a.z * b.w;
            acc[3][0] += a.w * b.x; acc[3][1] += a.w * b.y; acc[3][2] += a.w * b.z; acc[3][3] += a.w * b.w;
        }
        __syncthreads();
    }
    #pragma unroll
    for (int i = 0; i < 4; ++i) {
        const int r = ty * 4 + i;
        #pragma unroll
        for (int j = 0; j < 4; ++j) {
            const int cc = c0 + tx * 4 + j;
            Cp[(size_t)r * ldc + cc] = acc[i][j] + (biasp ? biasp[cc] : 0.f);
        }
    }
}

// ---------------------------------------------------------------------------
// Fused per-step kernel, wide: grid (64 b, 4 d-quadrants), 512 threads.
// scores+softmax (recomputed per quadrant, L2-dedup'd) -> float4 alpha@fW
// contraction split over 4 n-groups -> LDS reduce -> pointwise LSTM.
// ---------------------------------------------------------------------------
__global__ __launch_bounds__(512) void k_fused2(
    const float* __restrict__ u_hs,
    const float* __restrict__ A_w, const float* __restrict__ A_b,
    const float* __restrict__ wahp,  // [4][64][512]
    const float* __restrict__ ghhp,  // [4][64][2048]
    const float* __restrict__ pre_x, // [1920][2048] incl. ih_b+hh_b
    const float* __restrict__ fW,    // [64*49][2048]
    float* __restrict__ h_cur, float* __restrict__ c_cur,
    float* __restrict__ Hall, float* __restrict__ alphas,
    int s)
{
    const int bb = blockIdx.x;    // batch
    const int qq = blockIdx.y;    // d-quadrant
    const int tid = threadIdx.x;
    const int lane = tid & 63, w = tid >> 6;
    __shared__ float wah_l[512];
    __shared__ float awl[512];
    __shared__ float red[64];
    __shared__ float al[64];
    __shared__ float red4[4][128][4];
    __shared__ float gl[4][128];

    // stage wah (sum of 4 K-slices) + A_w  (coalesced)
    wah_l[tid] = wahp[bb * 512 + tid] + wahp[32768 + bb * 512 + tid]
               + wahp[65536 + bb * 512 + tid] + wahp[98304 + bb * 512 + tid];
    awl[tid] = A_w[tid];
    __syncthreads();

    // scores: 8 waves over 49 rows
    for (int n = w; n < NN; n += 8) {
        const float* up = u_hs + (size_t)(bb * NN + n) * 512;
        float acc = 0.f;
        #pragma unroll
        for (int i = 0; i < 8; ++i) {
            const int a = lane + i * 64;
            acc += awl[a] * fast_tanh(up[a] + wah_l[a]);
        }
        #pragma unroll
        for (int m = 32; m; m >>= 1) acc += __shfl_xor(acc, m, 64);
        if (lane == 0) red[n] = acc + A_b[0];
    }
    __syncthreads();

    // softmax over 49 in wave 0
    if (tid < 64) {
        const float sc = (tid < NN) ? red[tid] : -1e30f;
        float mx = sc;
        #pragma unroll
        for (int m = 32; m; m >>= 1) mx = fmaxf(mx, __shfl_xor(mx, m, 64));
        float e = (tid < NN) ? __expf(sc - mx) : 0.f;
        float sum = e;
        #pragma unroll
        for (int m = 32; m; m >>= 1) sum += __shfl_xor(sum, m, 64);
        const float av = e / sum;
        al[tid] = av;
        if (qq == 0 && tid < NN)
            alphas[(size_t)bb * (TT * NN) + (size_t)s * NN + tid] = av;
    }
    __syncthreads();

    // contraction: thread = (ngroup, gate, dq). float4 over 4 consecutive d.
    const int ng = tid >> 7;          // 0..3 n-group
    const int r = tid & 127;          // 0..127
    const int gate = r >> 5, dq = r & 31;
    const int j0 = gate * 512 + qq * 128 + dq * 4;
    const float* fb = fW + (size_t)bb * NN * 2048 + j0;
    f32x4 acc4 = {0.f, 0.f, 0.f, 0.f};
    for (int n = ng; n < NN; n += 4) {
        const float a = al[n];
        const f32x4 v = *(const f32x4*)(fb + (size_t)n * 2048);
        acc4[0] += a * v[0]; acc4[1] += a * v[1];
        acc4[2] += a * v[2]; acc4[3] += a * v[3];
    }
    *(f32x4*)&red4[ng][r][0] = acc4;
    __syncthreads();

    if (tid < 128) {
        const int gate2 = tid >> 5, dq2 = tid & 31;
        const int j = gate2 * 512 + qq * 128 + dq2 * 4;
        f32x4 sum = *(f32x4*)&red4[0][tid][0];
        #pragma unroll
        for (int k = 1; k < 4; ++k) {
            f32x4 v = *(f32x4*)&red4[k][tid][0];
            sum[0] += v[0]; sum[1] += v[1]; sum[2] += v[2]; sum[3] += v[3];
        }
        const f32x4 px = *(const f32x4*)(pre_x + (size_t)(s * 64 + bb) * 2048 + j);
        sum[0] += px[0]; sum[1] += px[1]; sum[2] += px[2]; sum[3] += px[3];
        const float* gp = ghhp + (size_t)bb * 2048 + j;
        #pragma unroll
        for (int ks = 0; ks < 4; ++ks) {
            const f32x4 v = *(const f32x4*)(gp + (size_t)ks * 131072);
            sum[0] += v[0]; sum[1] += v[1]; sum[2] += v[2]; sum[3] += v[3];
        }
        gl[gate2][dq2 * 4 + 0] = sum[0];
        gl[gate2][dq2 * 4 + 1] = sum[1];
        gl[gate2][dq2 * 4 + 2] = sum[2];
        gl[gate2][dq2 * 4 + 3] = sum[3];
    }
    __syncthreads();

    if (tid < 128) {
        const int dd = qq * 128 + tid;
        const float ig = sigmoidf(gl[0][tid]);
        const float fg = sigmoidf(gl[1][tid]);
        const float gg = fast_tanh(gl[2][tid]);
        const float og = sigmoidf(gl[3][tid]);
        const float cv = fg * c_cur[bb * 512 + dd] + ig * gg;
        const float hv = og * fast_tanh(cv);
        c_cur[bb * 512 + dd] = cv;
        h_cur[bb * 512 + dd] = hv;
        Hall[(size_t)(s * 64 + bb) * 512 + dd] = hv;
    }
}

// ---------------------------------------------------------------------------
extern "C" void kernel_launch(void* const* d_in, const int* in_sizes, int n_in,
                              void* d_out, int out_size, void* d_ws, size_t ws_size,
                              hipStream_t stream)
{
    const float* features = (const float*)d_in[0];
    const int*   captions = (const int*)d_in[1];
    const float* emb      = (const float*)d_in[2];
    const float* U_w      = (const float*)d_in[3];
    const float* U_b      = (const float*)d_in[4];
    const float* W_w      = (const float*)d_in[5];
    const float* W_b      = (const float*)d_in[6];
    const float* A_w      = (const float*)d_in[7];
    const float* A_b      = (const float*)d_in[8];
    const float* iH_w     = (const float*)d_in[9];
    const float* iH_b     = (const float*)d_in[10];
    const float* iC_w     = (const float*)d_in[11];
    const float* iC_b     = (const float*)d_in[12];
    const float* ih_w     = (const float*)d_in[13];
    const float* ih_b     = (const float*)d_in[14];
    const float* hh_w     = (const float*)d_in[15];
    const float* hh_b     = (const float*)d_in[16];
    const float* fcn_w    = (const float*)d_in[17];
    const float* fcn_b    = (const float*)d_in[18];

    float* out    = (float*)d_out;
    float* alphas = out + (size_t)B * TT * VOC;

    float* ws     = (float*)d_ws;
    float* fW     = ws;                       // 3136*2048 = 6,422,528
    float* u_hs   = fW + 6422528;             // 3136*512  = 1,605,632
    float* pre_x  = u_hs + 1605632;           // 1920*2048 = 3,932,160
    float* Hall   = pre_x + 3932160;          // 1920*512  = 983,040
    float* mean_f = Hall + 983040;            // 131,072
    float* h_cur  = mean_f + 131072;          // 32,768
    float* c_cur  = h_cur + 32768;            // 32,768
    float* embeds = c_cur + 32768;            // 1920*300  = 576,000
    float* bias2  = embeds + 576000;          // 2,048
    // aliases (producers dead before first use):
    float* pbuf   = fW;                       // init partials (dead before fW GEMM)
    float* wahp   = mean_f;                   // 4*64*512  = 131,072 (== mean_f size)
    float* ghhp   = embeds;                   // 4*64*2048 = 524,288 (<= embeds size)

    // init hidden state (split-K, fully parallel)
    k_mean<<<64, 256, 0, stream>>>(features, mean_f);
    k_init_partial<<<dim3(16, 16), 256, 0, stream>>>(mean_f, iH_w, iC_w, pbuf);
    k_init_reduce<<<256, 256, 0, stream>>>(pbuf, iH_b, iC_b, h_cur, c_cur);

    // hoisted precomputes
    k_embed<<<1920, 256, 0, stream>>>(captions, emb, embeds);
    k_bias2<<<8, 256, 0, stream>>>(ih_b, hh_b, bias2);
    // u_hs = features @ U_w^T + U_b                 [3136, 512]
    mfma_nt<<<dim3(4, 25), 512, 0, stream>>>(features, ENC, U_w, ENC, U_b, u_hs, ATT, B * NN, ATT, ENC, 0);
    // pre_x = embeds @ ih_w[:, :300]^T + (ih_b+hh_b) [1920, 2048]
    mfma_nt<<<dim3(16, 15), 512, 0, stream>>>(embeds, EMB, ih_w, 2348, bias2, pre_x, 2048, TT * B, 2048, EMB, 0);
    // fW = features @ ih_w[:, 300:2348]^T            [3136, 2048]
    mfma_nt<<<dim3(16, 25), 512, 0, stream>>>(features, ENC, ih_w + 300, 2348, nullptr, fW, 2048, B * NN, 2048, ENC, 0);

    // recurrence: 2 wide launches per step
    k_hw4<<<dim3(40, 4), 256, 0, stream>>>(h_cur, W_w, W_b, hh_w, wahp, ghhp);
    for (int s = 0; s < TT; ++s) {
        k_fused2<<<dim3(64, 4), 512, 0, stream>>>(u_hs, A_w, A_b, wahp, ghhp, pre_x, fW,
                                                  h_cur, c_cur, Hall, alphas, s);
        if (s < TT - 1)
            k_hw4<<<dim3(40, 4), 256, 0, stream>>>(h_cur, W_w, W_b, hh_w, wahp, ghhp);
    }

    // batched output projection
    mfma_nt<<<dim3(79, 15), 512, 0, stream>>>(Hall, DEC, fcn_w, DEC, fcn_b, out, VOC,
                                              TT * B, VOC, DEC, 1);
}

// Round 7
// 1049.865 us; speedup vs baseline: 3.0744x; 1.0599x over previous
//
#include <hip/hip_runtime.h>
#include <math.h>

// Problem constants
#define B 64
#define NN 49
#define ENC 2048
#define DEC 512
#define ATT 512
#define EMB 300
#define VOC 10000
#define TT 30

typedef __attribute__((ext_vector_type(4))) float f32x4;
typedef __attribute__((ext_vector_type(4))) short s16x4;
typedef __attribute__((ext_vector_type(8))) short s16x8;
typedef unsigned short u16;

__device__ __forceinline__ float fast_tanh(float x) {
    float e = __expf(2.f * x);
    return 1.f - 2.f / (e + 1.f);
}
__device__ __forceinline__ float sigmoidf(float x) {
    return 1.f / (1.f + __expf(-x));
}
__device__ __forceinline__ u16 f2bf(float x) {
    unsigned u = __float_as_uint(x);
    unsigned r = u + 0x7FFFu + ((u >> 16) & 1u);
    return (u16)(r >> 16);
}
__device__ __forceinline__ float bf2f(u16 u) {
    return __uint_as_float((unsigned)u << 16);
}
__device__ __forceinline__ void split_bf16(float x, short& hi, short& lo) {
    u16 h = f2bf(x);
    float hf = __uint_as_float((unsigned)h << 16);
    hi = (short)h;
    lo = (short)f2bf(x - hf);
}
__device__ __forceinline__ s16x8 ld8(const short* p) {
    s16x4 a = *(const s16x4*)p;
    s16x4 b = *(const s16x4*)(p + 4);
    return __builtin_shufflevector(a, b, 0, 1, 2, 3, 4, 5, 6, 7);
}

// ---------------------------------------------------------------------------
// Split-bf16 MFMA NT GEMM (f32 inputs): C = A@B^T (+bias).
// mode 0: f32 C. mode 1: f32 preds scatter. mode 2: bf16 (ushort) C.
// ---------------------------------------------------------------------------
__global__ __launch_bounds__(512) void mfma_nt(
    const float* __restrict__ A, int lda,
    const float* __restrict__ Bm, int ldb,
    const float* __restrict__ bias,
    float* __restrict__ C, int ldc,
    int M, int N, int K, int mode)
{
    __shared__ short Ah[128][40];
    __shared__ short Al[128][40];
    __shared__ short Bh[128][40];
    __shared__ short Bl[128][40];

    const int tid = threadIdx.x;
    const int m0 = blockIdx.y * 128, n0 = blockIdx.x * 128;
    const int wid = tid >> 6, lane = tid & 63;
    const int wm = wid >> 2, wn = wid & 3;
    const int lrow = lane & 15;
    const int lko = (lane >> 4) * 8;
    const int srow = tid >> 2;
    const int sk = (tid & 3) * 8;

    f32x4 acc[4][2];
    #pragma unroll
    for (int i = 0; i < 4; ++i)
        #pragma unroll
        for (int j = 0; j < 2; ++j)
            acc[i][j] = (f32x4){0.f, 0.f, 0.f, 0.f};

    const int nkt = (K + 31) >> 5;
    for (int kt = 0; kt < nkt; ++kt) {
        const int kb0 = kt * 32 + sk;
        {
            const int gr = m0 + srow;
            float v[8];
            if (gr < M && kb0 + 7 < K) {
                const float* p = A + (size_t)gr * lda + kb0;
                float4 x0 = *(const float4*)p;
                float4 x1 = *(const float4*)(p + 4);
                v[0] = x0.x; v[1] = x0.y; v[2] = x0.z; v[3] = x0.w;
                v[4] = x1.x; v[5] = x1.y; v[6] = x1.z; v[7] = x1.w;
            } else {
                #pragma unroll
                for (int j = 0; j < 8; ++j)
                    v[j] = (gr < M && kb0 + j < K) ? A[(size_t)gr * lda + kb0 + j] : 0.f;
            }
            s16x4 h0, h1, l0, l1;
            #pragma unroll
            for (int j = 0; j < 4; ++j) { short h, l; split_bf16(v[j], h, l); h0[j] = h; l0[j] = l; }
            #pragma unroll
            for (int j = 0; j < 4; ++j) { short h, l; split_bf16(v[4 + j], h, l); h1[j] = h; l1[j] = l; }
            *(s16x4*)&Ah[srow][sk] = h0; *(s16x4*)&Ah[srow][sk + 4] = h1;
            *(s16x4*)&Al[srow][sk] = l0; *(s16x4*)&Al[srow][sk + 4] = l1;
        }
        {
            const int gc = n0 + srow;
            float v[8];
            if (gc < N && kb0 + 7 < K) {
                const float* p = Bm + (size_t)gc * ldb + kb0;
                float4 x0 = *(const float4*)p;
                float4 x1 = *(const float4*)(p + 4);
                v[0] = x0.x; v[1] = x0.y; v[2] = x0.z; v[3] = x0.w;
                v[4] = x1.x; v[5] = x1.y; v[6] = x1.z; v[7] = x1.w;
            } else {
                #pragma unroll
                for (int j = 0; j < 8; ++j)
                    v[j] = (gc < N && kb0 + j < K) ? Bm[(size_t)gc * ldb + kb0 + j] : 0.f;
            }
            s16x4 h0, h1, l0, l1;
            #pragma unroll
            for (int j = 0; j < 4; ++j) { short h, l; split_bf16(v[j], h, l); h0[j] = h; l0[j] = l; }
            #pragma unroll
            for (int j = 0; j < 4; ++j) { short h, l; split_bf16(v[4 + j], h, l); h1[j] = h; l1[j] = l; }
            *(s16x4*)&Bh[srow][sk] = h0; *(s16x4*)&Bh[srow][sk + 4] = h1;
            *(s16x4*)&Bl[srow][sk] = l0; *(s16x4*)&Bl[srow][sk + 4] = l1;
        }
        __syncthreads();

        s16x8 bh[2], bl[2];
        #pragma unroll
        for (int nr = 0; nr < 2; ++nr) {
            const int col = wn * 32 + nr * 16 + lrow;
            bh[nr] = ld8(&Bh[col][lko]);
            bl[nr] = ld8(&Bl[col][lko]);
        }
        #pragma unroll
        for (int mr = 0; mr < 4; ++mr) {
            const int row = wm * 64 + mr * 16 + lrow;
            s16x8 ah = ld8(&Ah[row][lko]);
            s16x8 al = ld8(&Al[row][lko]);
            #pragma unroll
            for (int nr = 0; nr < 2; ++nr) {
                acc[mr][nr] = __builtin_amdgcn_mfma_f32_16x16x32_bf16(ah, bh[nr], acc[mr][nr], 0, 0, 0);
                acc[mr][nr] = __builtin_amdgcn_mfma_f32_16x16x32_bf16(ah, bl[nr], acc[mr][nr], 0, 0, 0);
                acc[mr][nr] = __builtin_amdgcn_mfma_f32_16x16x32_bf16(al, bh[nr], acc[mr][nr], 0, 0, 0);
            }
        }
        __syncthreads();
    }

    #pragma unroll
    for (int mr = 0; mr < 4; ++mr) {
        #pragma unroll
        for (int nr = 0; nr < 2; ++nr) {
            #pragma unroll
            for (int r = 0; r < 4; ++r) {
                const int row = m0 + wm * 64 + mr * 16 + (lane >> 4) * 4 + r;
                const int col = n0 + wn * 32 + nr * 16 + (lane & 15);
                if (row < M && col < N) {
                    float val = acc[mr][nr][r] + (bias ? bias[col] : 0.f);
                    if (mode == 0) C[(size_t)row * ldc + col] = val;
                    else if (mode == 1) {
                        const int t = row >> 6, bb = row & 63;
                        C[(size_t)bb * (TT * VOC) + (size_t)t * VOC + col] = val;
                    } else {
                        ((u16*)C)[(size_t)row * ldc + col] = f2bf(val);
                    }
                }
            }
        }
    }
}

// ---------------------------------------------------------------------------
// Pre-split bf16 MFMA GEMM: A (M x 512) hi/lo, B (N x 512) hi/lo, K=512.
// Output: preds scatter (mode 1) + bias.
// ---------------------------------------------------------------------------
__global__ __launch_bounds__(512) void mfma_pre(
    const u16* __restrict__ Ahg, const u16* __restrict__ Alg,
    const u16* __restrict__ Bhg, const u16* __restrict__ Blg,
    const float* __restrict__ bias,
    float* __restrict__ C, int M, int N)
{
    __shared__ short Ah[128][40];
    __shared__ short Al[128][40];
    __shared__ short Bh[128][40];
    __shared__ short Bl[128][40];

    const int tid = threadIdx.x;
    const int m0 = blockIdx.y * 128, n0 = blockIdx.x * 128;
    const int wid = tid >> 6, lane = tid & 63;
    const int wm = wid >> 2, wn = wid & 3;
    const int lrow = lane & 15;
    const int lko = (lane >> 4) * 8;
    const int srow = tid >> 2;
    const int sk = (tid & 3) * 8;

    f32x4 acc[4][2];
    #pragma unroll
    for (int i = 0; i < 4; ++i)
        #pragma unroll
        for (int j = 0; j < 2; ++j)
            acc[i][j] = (f32x4){0.f, 0.f, 0.f, 0.f};

    for (int kt = 0; kt < 16; ++kt) {
        const int kb0 = kt * 32 + sk;
        {
            const int gr = m0 + srow;
            s16x8 vh = {0,0,0,0,0,0,0,0}, vl = {0,0,0,0,0,0,0,0};
            if (gr < M) {
                vh = *(const s16x8*)(Ahg + (size_t)gr * 512 + kb0);
                vl = *(const s16x8*)(Alg + (size_t)gr * 512 + kb0);
            }
            *(s16x8*)&Ah[srow][sk] = vh;
            *(s16x8*)&Al[srow][sk] = vl;
        }
        {
            const int gc = n0 + srow;
            s16x8 vh = {0,0,0,0,0,0,0,0}, vl = {0,0,0,0,0,0,0,0};
            if (gc < N) {
                vh = *(const s16x8*)(Bhg + (size_t)gc * 512 + kb0);
                vl = *(const s16x8*)(Blg + (size_t)gc * 512 + kb0);
            }
            *(s16x8*)&Bh[srow][sk] = vh;
            *(s16x8*)&Bl[srow][sk] = vl;
        }
        __syncthreads();

        s16x8 bh[2], bl[2];
        #pragma unroll
        for (int nr = 0; nr < 2; ++nr) {
            const int col = wn * 32 + nr * 16 + lrow;
            bh[nr] = ld8(&Bh[col][lko]);
            bl[nr] = ld8(&Bl[col][lko]);
        }
        #pragma unroll
        for (int mr = 0; mr < 4; ++mr) {
            const int row = wm * 64 + mr * 16 + lrow;
            s16x8 ah = ld8(&Ah[row][lko]);
            s16x8 al = ld8(&Al[row][lko]);
            #pragma unroll
            for (int nr = 0; nr < 2; ++nr) {
                acc[mr][nr] = __builtin_amdgcn_mfma_f32_16x16x32_bf16(ah, bh[nr], acc[mr][nr], 0, 0, 0);
                acc[mr][nr] = __builtin_amdgcn_mfma_f32_16x16x32_bf16(ah, bl[nr], acc[mr][nr], 0, 0, 0);
                acc[mr][nr] = __builtin_amdgcn_mfma_f32_16x16x32_bf16(al, bh[nr], acc[mr][nr], 0, 0, 0);
            }
        }
        __syncthreads();
    }

    #pragma unroll
    for (int mr = 0; mr < 4; ++mr) {
        #pragma unroll
        for (int nr = 0; nr < 2; ++nr) {
            #pragma unroll
            for (int r = 0; r < 4; ++r) {
                const int row = m0 + wm * 64 + mr * 16 + (lane >> 4) * 4 + r;
                const int col = n0 + wn * 32 + nr * 16 + (lane & 15);
                if (row < M && col < N) {
                    const float val = acc[mr][nr][r] + bias[col];
                    const int t = row >> 6, bb = row & 63;
                    C[(size_t)bb * (TT * VOC) + (size_t)t * VOC + col] = val;
                }
            }
        }
    }
}

__global__ __launch_bounds__(256) void k_mean(const float* __restrict__ f,
                                              float* __restrict__ mean_f)
{
    const int b = blockIdx.x;
    for (int e = threadIdx.x; e < ENC; e += 256) {
        float s = 0.f;
        for (int n = 0; n < NN; ++n) s += f[(size_t)(b * NN + n) * ENC + e];
        mean_f[(size_t)b * ENC + e] = s * (1.f / 49.f);
    }
}

__global__ __launch_bounds__(256) void k_init_partial(
    const float* __restrict__ mean_f,
    const float* __restrict__ iH_w, const float* __restrict__ iC_w,
    float* __restrict__ pbuf)
{
    const int tid = threadIdx.x;
    const int tx = tid & 15, ty = tid >> 4;
    const int n0 = blockIdx.x * 64;
    const int ks = blockIdx.y;
    __shared__ float As[16][64];
    __shared__ float Bs[16][64];
    float acc[4][4] = {};
    const int lrow = tid >> 2;
    const int lk = (tid & 3) * 4;
    for (int c = 0; c < 8; ++c) {
        const int kk = ks * 128 + c * 16 + lk;
        float4 av = *(const float4*)(mean_f + (size_t)lrow * 2048 + kk);
        const int col = n0 + lrow;
        const float* wp = (col < 512) ? (iH_w + (size_t)col * 2048)
                                      : (iC_w + (size_t)(col - 512) * 2048);
        float4 bv = *(const float4*)(wp + kk);
        As[lk + 0][lrow] = av.x; As[lk + 1][lrow] = av.y;
        As[lk + 2][lrow] = av.z; As[lk + 3][lrow] = av.w;
        Bs[lk + 0][lrow] = bv.x; Bs[lk + 1][lrow] = bv.y;
        Bs[lk + 2][lrow] = bv.z; Bs[lk + 3][lrow] = bv.w;
        __syncthreads();
        #pragma unroll
        for (int k = 0; k < 16; ++k) {
            float4 a = *(const float4*)&As[k][ty * 4];
            float4 b = *(const float4*)&Bs[k][tx * 4];
            acc[0][0] += a.x * b.x; acc[0][1] += a.x * b.y; acc[0][2] += a.x * b.z; acc[0][3] += a.x * b.w;
            acc[1][0] += a.y * b.x; acc[1][1] += a.y * b.y; acc[1][2] += a.y * b.z; acc[1][3] += a.y * b.w;
            acc[2][0] += a.z * b.x; acc[2][1] += a.z * b.y; acc[2][2] += a.z * b.z; acc[2][3] += a.z * b.w;
            acc[3][0] += a.w * b.x; acc[3][1] += a.w * b.y; acc[3][2] += a.w * b.z; acc[3][3] += a.w * b.w;
        }
        __syncthreads();
    }
    #pragma unroll
    for (int i = 0; i < 4; ++i) {
        const int r = ty * 4 + i;
        #pragma unroll
        for (int j = 0; j < 4; ++j)
            pbuf[(size_t)(ks * 64 + r) * 1024 + n0 + tx * 4 + j] = acc[i][j];
    }
}

__global__ __launch_bounds__(256) void k_init_reduce(
    const float* __restrict__ pbuf,
    const float* __restrict__ iH_b, const float* __restrict__ iC_b,
    float* __restrict__ h_cur, float* __restrict__ c_cur)
{
    const int idx = blockIdx.x * 256 + threadIdx.x;
    const int r = idx >> 10, c = idx & 1023;
    float s = 0.f;
    #pragma unroll
    for (int ks = 0; ks < 16; ++ks) s += pbuf[(size_t)(ks * 64 + r) * 1024 + c];
    if (c < 512) h_cur[r * 512 + c] = s + iH_b[c];
    else         c_cur[r * 512 + (c - 512)] = s + iC_b[c - 512];
}

__global__ __launch_bounds__(256) void k_embed(const int* __restrict__ cap,
                                               const float* __restrict__ emb,
                                               float* __restrict__ embeds)
{
    const int r = blockIdx.x;
    const int t = r >> 6, b = r & 63;
    const int c = cap[b * 31 + t];
    for (int j = threadIdx.x; j < EMB; j += 256)
        embeds[(size_t)r * EMB + j] = emb[(size_t)c * EMB + j];
}

__global__ void k_bias2(const float* __restrict__ a, const float* __restrict__ b,
                        float* __restrict__ o)
{
    const int j = blockIdx.x * 256 + threadIdx.x;
    if (j < 2048) o[j] = a[j] + b[j];
}

// f32 -> (hi, lo) bf16 split of a flat array (n multiple of 4)
__global__ __launch_bounds__(256) void k_split(const float* __restrict__ src,
                                               u16* __restrict__ hi, u16* __restrict__ lo,
                                               int n)
{
    const int i = (blockIdx.x * 256 + threadIdx.x) * 4;
    if (i >= n) return;
    f32x4 v = *(const f32x4*)(src + i);
    s16x4 h4, l4;
    #pragma unroll
    for (int j = 0; j < 4; ++j) { short h, l; split_bf16(v[j], h, l); h4[j] = h; l4[j] = l; }
    *(s16x4*)(hi + i) = h4;
    *(s16x4*)(lo + i) = l4;
}

// ---------------------------------------------------------------------------
// wah/ghh split-K GEMV: grid (40, 4), 256 thr. 2-chunk staging, 4 barriers.
// cols 0..511 -> wahp[ks] (+W_b at ks 0); cols 512..2559 -> ghhp[ks].
// ---------------------------------------------------------------------------
__global__ __launch_bounds__(256) void k_hw4(
    const float* __restrict__ h,
    const float* __restrict__ W_w, const float* __restrict__ W_b,
    const float* __restrict__ hh_w,
    float* __restrict__ wahp, float* __restrict__ ghhp)
{
    const int tid = threadIdx.x;
    const int tx = tid & 15, ty = tid >> 4;
    const int n0 = blockIdx.x * 64;
    const int ks = blockIdx.y;
    const float* Bp; const float* biasp; float* Cp; int c0, ldc;
    if (n0 < 512) { Bp = W_w + (size_t)n0 * 512; biasp = (ks == 0) ? W_b : nullptr; Cp = wahp + (size_t)ks * 32768; c0 = n0; ldc = 512; }
    else { Bp = hh_w + (size_t)(n0 - 512) * 512; biasp = nullptr; Cp = ghhp + (size_t)ks * 131072; c0 = n0 - 512; ldc = 2048; }

    __shared__ float As[64][68];
    __shared__ float Bs[64][68];
    float acc[4][4] = {};
    const int rt = tid >> 2;
    const int cs = (tid & 3) * 16;

    for (int kh = 0; kh < 2; ++kh) {
        const int kbase = ks * 128 + kh * 64;
        #pragma unroll
        for (int i = 0; i < 4; ++i) {
            const int c = cs + i * 4;
            *(f32x4*)&As[rt][c] = *(const f32x4*)(h + (size_t)rt * 512 + kbase + c);
            *(f32x4*)&Bs[rt][c] = *(const f32x4*)(Bp + (size_t)rt * 512 + kbase + c);
        }
        __syncthreads();
        #pragma unroll
        for (int k4 = 0; k4 < 16; ++k4) {
            f32x4 a0 = *(const f32x4*)&As[ty * 4 + 0][k4 * 4];
            f32x4 a1 = *(const f32x4*)&As[ty * 4 + 1][k4 * 4];
            f32x4 a2 = *(const f32x4*)&As[ty * 4 + 2][k4 * 4];
            f32x4 a3 = *(const f32x4*)&As[ty * 4 + 3][k4 * 4];
            f32x4 b0 = *(const f32x4*)&Bs[tx * 4 + 0][k4 * 4];
            f32x4 b1 = *(const f32x4*)&Bs[tx * 4 + 1][k4 * 4];
            f32x4 b2 = *(const f32x4*)&Bs[tx * 4 + 2][k4 * 4];
            f32x4 b3 = *(const f32x4*)&Bs[tx * 4 + 3][k4 * 4];
            #pragma unroll
            for (int e = 0; e < 4; ++e) {
                acc[0][0] += a0[e] * b0[e]; acc[0][1] += a0[e] * b1[e];
                acc[0][2] += a0[e] * b2[e]; acc[0][3] += a0[e] * b3[e];
                acc[1][0] += a1[e] * b0[e]; acc[1][1] += a1[e] * b1[e];
                acc[1][2] += a1[e] * b2[e]; acc[1][3] += a1[e] * b3[e];
                acc[2][0] += a2[e] * b0[e]; acc[2][1] += a2[e] * b1[e];
                acc[2][2] += a2[e] * b2[e]; acc[2][3] += a2[e] * b3[e];
                acc[3][0] += a3[e] * b0[e]; acc[3][1] += a3[e] * b1[e];
                acc[3][2] += a3[e] * b2[e]; acc[3][3] += a3[e] * b3[e];
            }
        }
        __syncthreads();
    }
    #pragma unroll
    for (int i = 0; i < 4; ++i) {
        const int r = ty * 4 + i;
        #pragma unroll
        for (int j = 0; j < 4; ++j) {
            const int cc = c0 + tx * 4 + j;
            Cp[(size_t)r * ldc + cc] = acc[i][j] + (biasp ? biasp[cc] : 0.f);
        }
    }
}

// ---------------------------------------------------------------------------
// Fused per-step kernel v3: grid (64 b, 4 d-quadrants), 512 threads.
// All independent loads issued at entry (wah/ghh/pre_x/c/fW-fragments), then
// scores -> softmax -> shuffle-reduced bf16 fW contraction -> LSTM.
// ---------------------------------------------------------------------------
__global__ __launch_bounds__(512) void k_fused3(
    const u16* __restrict__ uhs16,
    const float* __restrict__ A_w, const float* __restrict__ A_b,
    const float* __restrict__ wahp,  // [4][64][512]
    const float* __restrict__ ghhp,  // [4][64][2048]
    const float* __restrict__ pre_x, // [1920][2048] incl. ih_b+hh_b
    const u16* __restrict__ fW16,    // [64*49][2048] bf16
    float* __restrict__ h_cur, float* __restrict__ c_cur,
    u16* __restrict__ Hall_h, u16* __restrict__ Hall_l,
    float* __restrict__ alphas, int s)
{
    const int bb = blockIdx.x;
    const int qq = blockIdx.y;
    const int tid = threadIdx.x;
    const int lane = tid & 63, w = tid >> 6;
    __shared__ float wah_l[512];
    __shared__ float awl[512];
    __shared__ float red[64];
    __shared__ float al[64];
    __shared__ float ghl[512];
    __shared__ float gl[512];

    // ---- issue all independent loads up front ----
    const int gate = tid >> 7, dloc = tid & 127;
    const int jcol = gate * 512 + qq * 128 + dloc;
    float ghv = pre_x[(size_t)(s * 64 + bb) * 2048 + jcol]
              + ghhp[(size_t)bb * 2048 + jcol]
              + ghhp[131072 + (size_t)bb * 2048 + jcol]
              + ghhp[262144 + (size_t)bb * 2048 + jcol]
              + ghhp[393216 + (size_t)bb * 2048 + jcol];
    float wv = wahp[bb * 512 + tid] + wahp[32768 + bb * 512 + tid]
             + wahp[65536 + bb * 512 + tid] + wahp[98304 + bb * 512 + tid];
    const float cload = c_cur[bb * 512 + qq * 128 + (tid & 127)];

    // fW fragment prefetch: thread = (ngf fast, colgroup)
    const int ngf = tid & 7, r = tid >> 3;
    const int gf = r >> 4, oc = r & 15;
    const int jb = gf * 512 + qq * 128 + oc * 8;
    const u16* fb = fW16 + (size_t)bb * NN * 2048 + jb;
    s16x8 pf[7];
    #pragma unroll
    for (int i = 0; i < 7; ++i) {
        const int n = ngf + 8 * i;
        if (n < NN) pf[i] = *(const s16x8*)(fb + (size_t)n * 2048);
        else        pf[i] = (s16x8){0, 0, 0, 0, 0, 0, 0, 0};
    }

    ghl[tid] = ghv;
    wah_l[tid] = wv;
    awl[tid] = A_w[tid];
    __syncthreads();

    // ---- scores ----
    for (int n = w; n < NN; n += 8) {
        const u16* up = uhs16 + (size_t)(bb * NN + n) * 512;
        float acc = 0.f;
        #pragma unroll
        for (int i = 0; i < 8; ++i) {
            const int a = lane + i * 64;
            acc += awl[a] * fast_tanh(bf2f(up[a]) + wah_l[a]);
        }
        #pragma unroll
        for (int m = 32; m; m >>= 1) acc += __shfl_xor(acc, m, 64);
        if (lane == 0) red[n] = acc + A_b[0];
    }
    __syncthreads();

    // ---- softmax (wave 0) ----
    if (tid < 64) {
        const float sc = (tid < NN) ? red[tid] : -1e30f;
        float mx = sc;
        #pragma unroll
        for (int m = 32; m; m >>= 1) mx = fmaxf(mx, __shfl_xor(mx, m, 64));
        float e = (tid < NN) ? __expf(sc - mx) : 0.f;
        float sum = e;
        #pragma unroll
        for (int m = 32; m; m >>= 1) sum += __shfl_xor(sum, m, 64);
        const float av = e / sum;
        al[tid] = av;
        if (qq == 0 && tid < NN)
            alphas[(size_t)bb * (TT * NN) + (size_t)s * NN + tid] = av;
    }
    __syncthreads();

    // ---- contraction from prefetched registers; 8-lane shuffle reduce ----
    float a8[8] = {0.f, 0.f, 0.f, 0.f, 0.f, 0.f, 0.f, 0.f};
    #pragma unroll
    for (int i = 0; i < 7; ++i) {
        const int n = ngf + 8 * i;          // <= 55 < 64; al[n>=49] == 0
        const float av = al[n];
        #pragma unroll
        for (int k = 0; k < 8; ++k)
            a8[k] += av * bf2f((u16)pf[i][k]);
    }
    #pragma unroll
    for (int m = 1; m < 8; m <<= 1)
        #pragma unroll
        for (int k = 0; k < 8; ++k)
            a8[k] += __shfl_xor(a8[k], m, 64);
    if (ngf == 0) {
        const int base = gf * 128 + oc * 8;
        #pragma unroll
        for (int k = 0; k < 8; ++k)
            gl[base + k] = a8[k] + ghl[base + k];
    }
    __syncthreads();

    // ---- pointwise LSTM ----
    if (tid < 128) {
        const int dd = qq * 128 + tid;
        const float ig = sigmoidf(gl[tid]);
        const float fg = sigmoidf(gl[128 + tid]);
        const float gg = fast_tanh(gl[256 + tid]);
        const float og = sigmoidf(gl[384 + tid]);
        const float cv = fg * cload + ig * gg;
        const float hv = og * fast_tanh(cv);
        c_cur[bb * 512 + dd] = cv;
        h_cur[bb * 512 + dd] = hv;
        short hh, hl;
        split_bf16(hv, hh, hl);
        Hall_h[(size_t)(s * 64 + bb) * 512 + dd] = (u16)hh;
        Hall_l[(size_t)(s * 64 + bb) * 512 + dd] = (u16)hl;
    }
}

// ---------------------------------------------------------------------------
extern "C" void kernel_launch(void* const* d_in, const int* in_sizes, int n_in,
                              void* d_out, int out_size, void* d_ws, size_t ws_size,
                              hipStream_t stream)
{
    const float* features = (const float*)d_in[0];
    const int*   captions = (const int*)d_in[1];
    const float* emb      = (const float*)d_in[2];
    const float* U_w      = (const float*)d_in[3];
    const float* U_b      = (const float*)d_in[4];
    const float* W_w      = (const float*)d_in[5];
    const float* W_b      = (const float*)d_in[6];
    const float* A_w      = (const float*)d_in[7];
    const float* A_b      = (const float*)d_in[8];
    const float* iH_w     = (const float*)d_in[9];
    const float* iH_b     = (const float*)d_in[10];
    const float* iC_w     = (const float*)d_in[11];
    const float* iC_b     = (const float*)d_in[12];
    const float* ih_w     = (const float*)d_in[13];
    const float* ih_b     = (const float*)d_in[14];
    const float* hh_w     = (const float*)d_in[15];
    const float* hh_b     = (const float*)d_in[16];
    const float* fcn_w    = (const float*)d_in[17];
    const float* fcn_b    = (const float*)d_in[18];

    float* out    = (float*)d_out;
    float* alphas = out + (size_t)B * TT * VOC;

    float* ws     = (float*)d_ws;
    // float-offset layout
    u16*  fW16    = (u16*)ws;                      // 6,422,528 u16 -> 3,211,264 f
    u16*  uhs16   = (u16*)(ws + 3211264);          // 1,605,632 u16 ->   802,816 f
    float* pre_x  = ws + 4014080;                  // 3,932,160 f
    u16*  Hall_h  = (u16*)(ws + 7946240);          //   983,040 u16 ->  491,520 f
    u16*  Hall_l  = (u16*)(ws + 8437760);          //   491,520 f
    float* mean_f = ws + 8929280;                  //   131,072
    float* h_cur  = ws + 9060352;                  //    32,768
    float* c_cur  = ws + 9093120;                  //    32,768
    float* wahp   = ws + 9125888;                  //   131,072 (4*64*512)
    float* ghhp   = ws + 9256960;                  //   524,288 (4*64*2048)
    float* embeds = ws + 9781248;                  //   576,000
    float* bias2  = ws + 10357248;                 //     2,048
    // aliases (dead producers):
    float* pbuf   = ws;                            // init partials (over fW16, dead before fW GEMM)
    u16*  fcnw_h  = (u16*)pre_x;                   // 5,120,000 u16 (after recurrence)
    u16*  fcnw_l  = (u16*)ws;                      // 5,120,000 u16 (after recurrence)

    // init hidden state
    k_mean<<<64, 256, 0, stream>>>(features, mean_f);
    k_init_partial<<<dim3(16, 16), 256, 0, stream>>>(mean_f, iH_w, iC_w, pbuf);
    k_init_reduce<<<256, 256, 0, stream>>>(pbuf, iH_b, iC_b, h_cur, c_cur);

    // hoisted precomputes
    k_embed<<<1920, 256, 0, stream>>>(captions, emb, embeds);
    k_bias2<<<8, 256, 0, stream>>>(ih_b, hh_b, bias2);
    // u_hs (bf16) = features @ U_w^T + U_b              [3136, 512]
    mfma_nt<<<dim3(4, 25), 512, 0, stream>>>(features, ENC, U_w, ENC, U_b, (float*)uhs16, ATT, B * NN, ATT, ENC, 2);
    // pre_x (f32) = embeds @ ih_w[:, :300]^T + bias2    [1920, 2048]
    mfma_nt<<<dim3(16, 15), 512, 0, stream>>>(embeds, EMB, ih_w, 2348, bias2, pre_x, 2048, TT * B, 2048, EMB, 0);
    // fW (bf16) = features @ ih_w[:, 300:2348]^T        [3136, 2048]
    mfma_nt<<<dim3(16, 25), 512, 0, stream>>>(features, ENC, ih_w + 300, 2348, nullptr, (float*)fW16, 2048, B * NN, 2048, ENC, 2);

    // recurrence
    k_hw4<<<dim3(40, 4), 256, 0, stream>>>(h_cur, W_w, W_b, hh_w, wahp, ghhp);
    for (int s = 0; s < TT; ++s) {
        k_fused3<<<dim3(64, 4), 512, 0, stream>>>(uhs16, A_w, A_b, wahp, ghhp, pre_x, fW16,
                                                  h_cur, c_cur, Hall_h, Hall_l, alphas, s);
        if (s < TT - 1)
            k_hw4<<<dim3(40, 4), 256, 0, stream>>>(h_cur, W_w, W_b, hh_w, wahp, ghhp);
    }

    // output projection on pre-split bf16 (fcn_w split into dead ws space)
    k_split<<<5000, 256, 0, stream>>>(fcn_w, fcnw_h, fcnw_l, VOC * DEC);
    mfma_pre<<<dim3(79, 15), 512, 0, stream>>>(Hall_h, Hall_l, fcnw_h, fcnw_l, fcn_b,
                                               out, TT * B, VOC);
}

// Round 8
// 925.085 us; speedup vs baseline: 3.4891x; 1.1349x over previous
//
#include <hip/hip_runtime.h>
#include <math.h>

// Problem constants
#define B 64
#define NN 49
#define ENC 2048
#define DEC 512
#define ATT 512
#define EMB 300
#define VOC 10000
#define TT 30

typedef __attribute__((ext_vector_type(4))) float f32x4;
typedef __attribute__((ext_vector_type(4))) short s16x4;
typedef __attribute__((ext_vector_type(8))) short s16x8;
typedef unsigned short u16;

__device__ __forceinline__ float fast_tanh(float x) {
    float e = __expf(2.f * x);
    return 1.f - 2.f / (e + 1.f);
}
__device__ __forceinline__ float sigmoidf(float x) {
    return 1.f / (1.f + __expf(-x));
}
__device__ __forceinline__ u16 f2bf(float x) {
    unsigned u = __float_as_uint(x);
    unsigned r = u + 0x7FFFu + ((u >> 16) & 1u);
    return (u16)(r >> 16);
}
__device__ __forceinline__ float bf2f(u16 u) {
    return __uint_as_float((unsigned)u << 16);
}
__device__ __forceinline__ void split_bf16(float x, short& hi, short& lo) {
    u16 h = f2bf(x);
    float hf = __uint_as_float((unsigned)h << 16);
    hi = (short)h;
    lo = (short)f2bf(x - hf);
}
__device__ __forceinline__ s16x8 ld8(const short* p) {
    s16x4 a = *(const s16x4*)p;
    s16x4 b = *(const s16x4*)(p + 4);
    return __builtin_shufflevector(a, b, 0, 1, 2, 3, 4, 5, 6, 7);
}

// ---------------------------------------------------------------------------
// Split-bf16 MFMA NT GEMM (f32 inputs): C = A@B^T (+bias). mode 0: f32 C.
// ---------------------------------------------------------------------------
__global__ __launch_bounds__(512) void mfma_nt(
    const float* __restrict__ A, int lda,
    const float* __restrict__ Bm, int ldb,
    const float* __restrict__ bias,
    float* __restrict__ C, int ldc,
    int M, int N, int K, int mode)
{
    __shared__ short Ah[128][40];
    __shared__ short Al[128][40];
    __shared__ short Bh[128][40];
    __shared__ short Bl[128][40];

    const int tid = threadIdx.x;
    const int m0 = blockIdx.y * 128, n0 = blockIdx.x * 128;
    const int wid = tid >> 6, lane = tid & 63;
    const int wm = wid >> 2, wn = wid & 3;
    const int lrow = lane & 15;
    const int lko = (lane >> 4) * 8;
    const int srow = tid >> 2;
    const int sk = (tid & 3) * 8;

    f32x4 acc[4][2];
    #pragma unroll
    for (int i = 0; i < 4; ++i)
        #pragma unroll
        for (int j = 0; j < 2; ++j)
            acc[i][j] = (f32x4){0.f, 0.f, 0.f, 0.f};

    const int nkt = (K + 31) >> 5;
    for (int kt = 0; kt < nkt; ++kt) {
        const int kb0 = kt * 32 + sk;
        {
            const int gr = m0 + srow;
            float v[8];
            if (gr < M && kb0 + 7 < K) {
                const float* p = A + (size_t)gr * lda + kb0;
                float4 x0 = *(const float4*)p;
                float4 x1 = *(const float4*)(p + 4);
                v[0] = x0.x; v[1] = x0.y; v[2] = x0.z; v[3] = x0.w;
                v[4] = x1.x; v[5] = x1.y; v[6] = x1.z; v[7] = x1.w;
            } else {
                #pragma unroll
                for (int j = 0; j < 8; ++j)
                    v[j] = (gr < M && kb0 + j < K) ? A[(size_t)gr * lda + kb0 + j] : 0.f;
            }
            s16x4 h0, h1, l0, l1;
            #pragma unroll
            for (int j = 0; j < 4; ++j) { short h, l; split_bf16(v[j], h, l); h0[j] = h; l0[j] = l; }
            #pragma unroll
            for (int j = 0; j < 4; ++j) { short h, l; split_bf16(v[4 + j], h, l); h1[j] = h; l1[j] = l; }
            *(s16x4*)&Ah[srow][sk] = h0; *(s16x4*)&Ah[srow][sk + 4] = h1;
            *(s16x4*)&Al[srow][sk] = l0; *(s16x4*)&Al[srow][sk + 4] = l1;
        }
        {
            const int gc = n0 + srow;
            float v[8];
            if (gc < N && kb0 + 7 < K) {
                const float* p = Bm + (size_t)gc * ldb + kb0;
                float4 x0 = *(const float4*)p;
                float4 x1 = *(const float4*)(p + 4);
                v[0] = x0.x; v[1] = x0.y; v[2] = x0.z; v[3] = x0.w;
                v[4] = x1.x; v[5] = x1.y; v[6] = x1.z; v[7] = x1.w;
            } else {
                #pragma unroll
                for (int j = 0; j < 8; ++j)
                    v[j] = (gc < N && kb0 + j < K) ? Bm[(size_t)gc * ldb + kb0 + j] : 0.f;
            }
            s16x4 h0, h1, l0, l1;
            #pragma unroll
            for (int j = 0; j < 4; ++j) { short h, l; split_bf16(v[j], h, l); h0[j] = h; l0[j] = l; }
            #pragma unroll
            for (int j = 0; j < 4; ++j) { short h, l; split_bf16(v[4 + j], h, l); h1[j] = h; l1[j] = l; }
            *(s16x4*)&Bh[srow][sk] = h0; *(s16x4*)&Bh[srow][sk + 4] = h1;
            *(s16x4*)&Bl[srow][sk] = l0; *(s16x4*)&Bl[srow][sk + 4] = l1;
        }
        __syncthreads();

        s16x8 bh[2], bl[2];
        #pragma unroll
        for (int nr = 0; nr < 2; ++nr) {
            const int col = wn * 32 + nr * 16 + lrow;
            bh[nr] = ld8(&Bh[col][lko]);
            bl[nr] = ld8(&Bl[col][lko]);
        }
        #pragma unroll
        for (int mr = 0; mr < 4; ++mr) {
            const int row = wm * 64 + mr * 16 + lrow;
            s16x8 ah = ld8(&Ah[row][lko]);
            s16x8 al = ld8(&Al[row][lko]);
            #pragma unroll
            for (int nr = 0; nr < 2; ++nr) {
                acc[mr][nr] = __builtin_amdgcn_mfma_f32_16x16x32_bf16(ah, bh[nr], acc[mr][nr], 0, 0, 0);
                acc[mr][nr] = __builtin_amdgcn_mfma_f32_16x16x32_bf16(ah, bl[nr], acc[mr][nr], 0, 0, 0);
                acc[mr][nr] = __builtin_amdgcn_mfma_f32_16x16x32_bf16(al, bh[nr], acc[mr][nr], 0, 0, 0);
            }
        }
        __syncthreads();
    }

    #pragma unroll
    for (int mr = 0; mr < 4; ++mr) {
        #pragma unroll
        for (int nr = 0; nr < 2; ++nr) {
            #pragma unroll
            for (int r = 0; r < 4; ++r) {
                const int row = m0 + wm * 64 + mr * 16 + (lane >> 4) * 4 + r;
                const int col = n0 + wn * 32 + nr * 16 + (lane & 15);
                if (row < M && col < N)
                    C[(size_t)row * ldc + col] = acc[mr][nr][r] + (bias ? bias[col] : 0.f);
            }
        }
    }
}

// ---------------------------------------------------------------------------
// Combined u_hs+fW GEMM: A = pre-split features (hi/lo bf16, [3136][2048]),
// B = concat(U_w, ih_w[:,300:2348]) split on the fly. K=2048, N=2560.
// col<512 -> uhs16 (+U_b); col>=512 -> fW16. bf16 outputs.
// ---------------------------------------------------------------------------
__global__ __launch_bounds__(512) void mfma_cat(
    const u16* __restrict__ fhi, const u16* __restrict__ flo,
    const float* __restrict__ U_w, const float* __restrict__ U_b,
    const float* __restrict__ ih_w,
    u16* __restrict__ uhs16, u16* __restrict__ fW16, int M)
{
    __shared__ short Ah[128][40];
    __shared__ short Al[128][40];
    __shared__ short Bh[128][40];
    __shared__ short Bl[128][40];

    const int tid = threadIdx.x;
    const int m0 = blockIdx.y * 128, n0 = blockIdx.x * 128;
    const int wid = tid >> 6, lane = tid & 63;
    const int wm = wid >> 2, wn = wid & 3;
    const int lrow = lane & 15;
    const int lko = (lane >> 4) * 8;
    const int srow = tid >> 2;
    const int sk = (tid & 3) * 8;

    const int gc = n0 + srow;   // < 2560 always
    const float* bp = (gc < 512) ? (U_w + (size_t)gc * 2048)
                                 : (ih_w + (size_t)(gc - 512) * 2348 + 300);
    const int gr = m0 + srow;
    const u16* ahp = fhi + (size_t)gr * 2048;
    const u16* alp = flo + (size_t)gr * 2048;

    f32x4 acc[4][2];
    #pragma unroll
    for (int i = 0; i < 4; ++i)
        #pragma unroll
        for (int j = 0; j < 2; ++j)
            acc[i][j] = (f32x4){0.f, 0.f, 0.f, 0.f};

    for (int kt = 0; kt < 64; ++kt) {
        const int kb0 = kt * 32 + sk;
        {
            s16x8 vh = {0,0,0,0,0,0,0,0}, vl = {0,0,0,0,0,0,0,0};
            if (gr < M) {
                vh = *(const s16x8*)(ahp + kb0);
                vl = *(const s16x8*)(alp + kb0);
            }
            *(s16x8*)&Ah[srow][sk] = vh;
            *(s16x8*)&Al[srow][sk] = vl;
        }
        {
            float4 x0 = *(const float4*)(bp + kb0);
            float4 x1 = *(const float4*)(bp + kb0 + 4);
            float v[8] = {x0.x, x0.y, x0.z, x0.w, x1.x, x1.y, x1.z, x1.w};
            s16x4 h0, h1, l0, l1;
            #pragma unroll
            for (int j = 0; j < 4; ++j) { short h, l; split_bf16(v[j], h, l); h0[j] = h; l0[j] = l; }
            #pragma unroll
            for (int j = 0; j < 4; ++j) { short h, l; split_bf16(v[4 + j], h, l); h1[j] = h; l1[j] = l; }
            *(s16x4*)&Bh[srow][sk] = h0; *(s16x4*)&Bh[srow][sk + 4] = h1;
            *(s16x4*)&Bl[srow][sk] = l0; *(s16x4*)&Bl[srow][sk + 4] = l1;
        }
        __syncthreads();

        s16x8 bh[2], bl[2];
        #pragma unroll
        for (int nr = 0; nr < 2; ++nr) {
            const int col = wn * 32 + nr * 16 + lrow;
            bh[nr] = ld8(&Bh[col][lko]);
            bl[nr] = ld8(&Bl[col][lko]);
        }
        #pragma unroll
        for (int mr = 0; mr < 4; ++mr) {
            const int row = wm * 64 + mr * 16 + lrow;
            s16x8 ah = ld8(&Ah[row][lko]);
            s16x8 al = ld8(&Al[row][lko]);
            #pragma unroll
            for (int nr = 0; nr < 2; ++nr) {
                acc[mr][nr] = __builtin_amdgcn_mfma_f32_16x16x32_bf16(ah, bh[nr], acc[mr][nr], 0, 0, 0);
                acc[mr][nr] = __builtin_amdgcn_mfma_f32_16x16x32_bf16(ah, bl[nr], acc[mr][nr], 0, 0, 0);
                acc[mr][nr] = __builtin_amdgcn_mfma_f32_16x16x32_bf16(al, bh[nr], acc[mr][nr], 0, 0, 0);
            }
        }
        __syncthreads();
    }

    #pragma unroll
    for (int mr = 0; mr < 4; ++mr) {
        #pragma unroll
        for (int nr = 0; nr < 2; ++nr) {
            #pragma unroll
            for (int r = 0; r < 4; ++r) {
                const int row = m0 + wm * 64 + mr * 16 + (lane >> 4) * 4 + r;
                const int col = n0 + wn * 32 + nr * 16 + (lane & 15);
                if (row < M) {
                    if (col < 512)
                        uhs16[(size_t)row * 512 + col] = f2bf(acc[mr][nr][r] + U_b[col]);
                    else
                        fW16[(size_t)row * 2048 + (col - 512)] = f2bf(acc[mr][nr][r]);
                }
            }
        }
    }
}

// ---------------------------------------------------------------------------
// Pre-split bf16 MFMA GEMM: K=512, preds scatter + bias.
// ---------------------------------------------------------------------------
__global__ __launch_bounds__(512) void mfma_pre(
    const u16* __restrict__ Ahg, const u16* __restrict__ Alg,
    const u16* __restrict__ Bhg, const u16* __restrict__ Blg,
    const float* __restrict__ bias,
    float* __restrict__ C, int M, int N)
{
    __shared__ short Ah[128][40];
    __shared__ short Al[128][40];
    __shared__ short Bh[128][40];
    __shared__ short Bl[128][40];

    const int tid = threadIdx.x;
    const int m0 = blockIdx.y * 128, n0 = blockIdx.x * 128;
    const int wid = tid >> 6, lane = tid & 63;
    const int wm = wid >> 2, wn = wid & 3;
    const int lrow = lane & 15;
    const int lko = (lane >> 4) * 8;
    const int srow = tid >> 2;
    const int sk = (tid & 3) * 8;

    f32x4 acc[4][2];
    #pragma unroll
    for (int i = 0; i < 4; ++i)
        #pragma unroll
        for (int j = 0; j < 2; ++j)
            acc[i][j] = (f32x4){0.f, 0.f, 0.f, 0.f};

    for (int kt = 0; kt < 16; ++kt) {
        const int kb0 = kt * 32 + sk;
        {
            const int gr = m0 + srow;
            s16x8 vh = {0,0,0,0,0,0,0,0}, vl = {0,0,0,0,0,0,0,0};
            if (gr < M) {
                vh = *(const s16x8*)(Ahg + (size_t)gr * 512 + kb0);
                vl = *(const s16x8*)(Alg + (size_t)gr * 512 + kb0);
            }
            *(s16x8*)&Ah[srow][sk] = vh;
            *(s16x8*)&Al[srow][sk] = vl;
        }
        {
            const int gc = n0 + srow;
            s16x8 vh = {0,0,0,0,0,0,0,0}, vl = {0,0,0,0,0,0,0,0};
            if (gc < N) {
                vh = *(const s16x8*)(Bhg + (size_t)gc * 512 + kb0);
                vl = *(const s16x8*)(Blg + (size_t)gc * 512 + kb0);
            }
            *(s16x8*)&Bh[srow][sk] = vh;
            *(s16x8*)&Bl[srow][sk] = vl;
        }
        __syncthreads();

        s16x8 bh[2], bl[2];
        #pragma unroll
        for (int nr = 0; nr < 2; ++nr) {
            const int col = wn * 32 + nr * 16 + lrow;
            bh[nr] = ld8(&Bh[col][lko]);
            bl[nr] = ld8(&Bl[col][lko]);
        }
        #pragma unroll
        for (int mr = 0; mr < 4; ++mr) {
            const int row = wm * 64 + mr * 16 + lrow;
            s16x8 ah = ld8(&Ah[row][lko]);
            s16x8 al = ld8(&Al[row][lko]);
            #pragma unroll
            for (int nr = 0; nr < 2; ++nr) {
                acc[mr][nr] = __builtin_amdgcn_mfma_f32_16x16x32_bf16(ah, bh[nr], acc[mr][nr], 0, 0, 0);
                acc[mr][nr] = __builtin_amdgcn_mfma_f32_16x16x32_bf16(ah, bl[nr], acc[mr][nr], 0, 0, 0);
                acc[mr][nr] = __builtin_amdgcn_mfma_f32_16x16x32_bf16(al, bh[nr], acc[mr][nr], 0, 0, 0);
            }
        }
        __syncthreads();
    }

    #pragma unroll
    for (int mr = 0; mr < 4; ++mr) {
        #pragma unroll
        for (int nr = 0; nr < 2; ++nr) {
            #pragma unroll
            for (int r = 0; r < 4; ++r) {
                const int row = m0 + wm * 64 + mr * 16 + (lane >> 4) * 4 + r;
                const int col = n0 + wn * 32 + nr * 16 + (lane & 15);
                if (row < M && col < N) {
                    const float val = acc[mr][nr][r] + bias[col];
                    const int t = row >> 6, bb = row & 63;
                    C[(size_t)bb * (TT * VOC) + (size_t)t * VOC + col] = val;
                }
            }
        }
    }
}

__global__ __launch_bounds__(256) void k_mean(const float* __restrict__ f,
                                              float* __restrict__ mean_f)
{
    const int b = blockIdx.x;
    for (int e = threadIdx.x; e < ENC; e += 256) {
        float s = 0.f;
        for (int n = 0; n < NN; ++n) s += f[(size_t)(b * NN + n) * ENC + e];
        mean_f[(size_t)b * ENC + e] = s * (1.f / 49.f);
    }
}

__global__ __launch_bounds__(256) void k_init_partial(
    const float* __restrict__ mean_f,
    const float* __restrict__ iH_w, const float* __restrict__ iC_w,
    float* __restrict__ pbuf)
{
    const int tid = threadIdx.x;
    const int tx = tid & 15, ty = tid >> 4;
    const int n0 = blockIdx.x * 64;
    const int ks = blockIdx.y;
    __shared__ float As[16][64];
    __shared__ float Bs[16][64];
    float acc[4][4] = {};
    const int lrow = tid >> 2;
    const int lk = (tid & 3) * 4;
    for (int c = 0; c < 8; ++c) {
        const int kk = ks * 128 + c * 16 + lk;
        float4 av = *(const float4*)(mean_f + (size_t)lrow * 2048 + kk);
        const int col = n0 + lrow;
        const float* wp = (col < 512) ? (iH_w + (size_t)col * 2048)
                                      : (iC_w + (size_t)(col - 512) * 2048);
        float4 bv = *(const float4*)(wp + kk);
        As[lk + 0][lrow] = av.x; As[lk + 1][lrow] = av.y;
        As[lk + 2][lrow] = av.z; As[lk + 3][lrow] = av.w;
        Bs[lk + 0][lrow] = bv.x; Bs[lk + 1][lrow] = bv.y;
        Bs[lk + 2][lrow] = bv.z; Bs[lk + 3][lrow] = bv.w;
        __syncthreads();
        #pragma unroll
        for (int k = 0; k < 16; ++k) {
            float4 a = *(const float4*)&As[k][ty * 4];
            float4 b = *(const float4*)&Bs[k][tx * 4];
            acc[0][0] += a.x * b.x; acc[0][1] += a.x * b.y; acc[0][2] += a.x * b.z; acc[0][3] += a.x * b.w;
            acc[1][0] += a.y * b.x; acc[1][1] += a.y * b.y; acc[1][2] += a.y * b.z; acc[1][3] += a.y * b.w;
            acc[2][0] += a.z * b.x; acc[2][1] += a.z * b.y; acc[2][2] += a.z * b.z; acc[2][3] += a.z * b.w;
            acc[3][0] += a.w * b.x; acc[3][1] += a.w * b.y; acc[3][2] += a.w * b.z; acc[3][3] += a.w * b.w;
        }
        __syncthreads();
    }
    #pragma unroll
    for (int i = 0; i < 4; ++i) {
        const int r = ty * 4 + i;
        #pragma unroll
        for (int j = 0; j < 4; ++j)
            pbuf[(size_t)(ks * 64 + r) * 1024 + n0 + tx * 4 + j] = acc[i][j];
    }
}

__global__ __launch_bounds__(256) void k_init_reduce(
    const float* __restrict__ pbuf,
    const float* __restrict__ iH_b, const float* __restrict__ iC_b,
    float* __restrict__ h_cur, float* __restrict__ c_cur)
{
    const int idx = blockIdx.x * 256 + threadIdx.x;
    const int r = idx >> 10, c = idx & 1023;
    float s = 0.f;
    #pragma unroll
    for (int ks = 0; ks < 16; ++ks) s += pbuf[(size_t)(ks * 64 + r) * 1024 + c];
    if (c < 512) h_cur[r * 512 + c] = s + iH_b[c];
    else         c_cur[r * 512 + (c - 512)] = s + iC_b[c - 512];
}

__global__ __launch_bounds__(256) void k_embed(const int* __restrict__ cap,
                                               const float* __restrict__ emb,
                                               float* __restrict__ embeds)
{
    const int r = blockIdx.x;
    const int t = r >> 6, b = r & 63;
    const int c = cap[b * 31 + t];
    for (int j = threadIdx.x; j < EMB; j += 256)
        embeds[(size_t)r * EMB + j] = emb[(size_t)c * EMB + j];
}

__global__ void k_bias2(const float* __restrict__ a, const float* __restrict__ b,
                        float* __restrict__ o)
{
    const int j = blockIdx.x * 256 + threadIdx.x;
    if (j < 2048) o[j] = a[j] + b[j];
}

// f32 -> (hi, lo) bf16 split of a flat array (n multiple of 4)
__global__ __launch_bounds__(256) void k_split(const float* __restrict__ src,
                                               u16* __restrict__ hi, u16* __restrict__ lo,
                                               int n)
{
    const int i = (blockIdx.x * 256 + threadIdx.x) * 4;
    if (i >= n) return;
    f32x4 v = *(const f32x4*)(src + i);
    s16x4 h4, l4;
    #pragma unroll
    for (int j = 0; j < 4; ++j) { short h, l; split_bf16(v[j], h, l); h4[j] = h; l4[j] = l; }
    *(s16x4*)(hi + i) = h4;
    *(s16x4*)(lo + i) = l4;
}

// ---------------------------------------------------------------------------
// wah/ghh split-K GEMV: grid (40, 4), 256 thr.
// ---------------------------------------------------------------------------
__global__ __launch_bounds__(256) void k_hw4(
    const float* __restrict__ h,
    const float* __restrict__ W_w, const float* __restrict__ W_b,
    const float* __restrict__ hh_w,
    float* __restrict__ wahp, float* __restrict__ ghhp)
{
    const int tid = threadIdx.x;
    const int tx = tid & 15, ty = tid >> 4;
    const int n0 = blockIdx.x * 64;
    const int ks = blockIdx.y;
    const float* Bp; const float* biasp; float* Cp; int c0, ldc;
    if (n0 < 512) { Bp = W_w + (size_t)n0 * 512; biasp = (ks == 0) ? W_b : nullptr; Cp = wahp + (size_t)ks * 32768; c0 = n0; ldc = 512; }
    else { Bp = hh_w + (size_t)(n0 - 512) * 512; biasp = nullptr; Cp = ghhp + (size_t)ks * 131072; c0 = n0 - 512; ldc = 2048; }

    __shared__ float As[64][68];
    __shared__ float Bs[64][68];
    float acc[4][4] = {};
    const int rt = tid >> 2;
    const int cs = (tid & 3) * 16;

    for (int kh = 0; kh < 2; ++kh) {
        const int kbase = ks * 128 + kh * 64;
        #pragma unroll
        for (int i = 0; i < 4; ++i) {
            const int c = cs + i * 4;
            *(f32x4*)&As[rt][c] = *(const f32x4*)(h + (size_t)rt * 512 + kbase + c);
            *(f32x4*)&Bs[rt][c] = *(const f32x4*)(Bp + (size_t)rt * 512 + kbase + c);
        }
        __syncthreads();
        #pragma unroll
        for (int k4 = 0; k4 < 16; ++k4) {
            f32x4 a0 = *(const f32x4*)&As[ty * 4 + 0][k4 * 4];
            f32x4 a1 = *(const f32x4*)&As[ty * 4 + 1][k4 * 4];
            f32x4 a2 = *(const f32x4*)&As[ty * 4 + 2][k4 * 4];
            f32x4 a3 = *(const f32x4*)&As[ty * 4 + 3][k4 * 4];
            f32x4 b0 = *(const f32x4*)&Bs[tx * 4 + 0][k4 * 4];
            f32x4 b1 = *(const f32x4*)&Bs[tx * 4 + 1][k4 * 4];
            f32x4 b2 = *(const f32x4*)&Bs[tx * 4 + 2][k4 * 4];
            f32x4 b3 = *(const f32x4*)&Bs[tx * 4 + 3][k4 * 4];
            #pragma unroll
            for (int e = 0; e < 4; ++e) {
                acc[0][0] += a0[e] * b0[e]; acc[0][1] += a0[e] * b1[e];
                acc[0][2] += a0[e] * b2[e]; acc[0][3] += a0[e] * b3[e];
                acc[1][0] += a1[e] * b0[e]; acc[1][1] += a1[e] * b1[e];
                acc[1][2] += a1[e] * b2[e]; acc[1][3] += a1[e] * b3[e];
                acc[2][0] += a2[e] * b0[e]; acc[2][1] += a2[e] * b1[e];
                acc[2][2] += a2[e] * b2[e]; acc[2][3] += a2[e] * b3[e];
                acc[3][0] += a3[e] * b0[e]; acc[3][1] += a3[e] * b1[e];
                acc[3][2] += a3[e] * b2[e]; acc[3][3] += a3[e] * b3[e];
            }
        }
        __syncthreads();
    }
    #pragma unroll
    for (int i = 0; i < 4; ++i) {
        const int r = ty * 4 + i;
        #pragma unroll
        for (int j = 0; j < 4; ++j) {
            const int cc = c0 + tx * 4 + j;
            Cp[(size_t)r * ldc + cc] = acc[i][j] + (biasp ? biasp[cc] : 0.f);
        }
    }
}

// ---------------------------------------------------------------------------
// Fused per-step kernel v4: grid (64 b, 4 d-quadrants), 512 threads.
// Coalesced per-lane-contiguous score loads; all independent loads up front.
// ---------------------------------------------------------------------------
__global__ __launch_bounds__(512) void k_fused4(
    const u16* __restrict__ uhs16,
    const float* __restrict__ A_w, const float* __restrict__ A_b,
    const float* __restrict__ wahp,  // [4][64][512]
    const float* __restrict__ ghhp,  // [4][64][2048]
    const float* __restrict__ pre_x, // [1920][2048] incl. ih_b+hh_b
    const u16* __restrict__ fW16,    // [64*49][2048] bf16
    float* __restrict__ h_cur, float* __restrict__ c_cur,
    u16* __restrict__ Hall_h, u16* __restrict__ Hall_l,
    float* __restrict__ alphas, int s)
{
    const int bb = blockIdx.x;
    const int qq = blockIdx.y;
    const int tid = threadIdx.x;
    const int lane = tid & 63, w = tid >> 6;
    __shared__ float wah_l[512];
    __shared__ float red[64];
    __shared__ float al[64];
    __shared__ float ghl[512];
    __shared__ float gl[512];

    // ---- independent loads up front ----
    const int gate = tid >> 7, dloc = tid & 127;
    const int jcol = gate * 512 + qq * 128 + dloc;
    float ghv = pre_x[(size_t)(s * 64 + bb) * 2048 + jcol]
              + ghhp[(size_t)bb * 2048 + jcol]
              + ghhp[131072 + (size_t)bb * 2048 + jcol]
              + ghhp[262144 + (size_t)bb * 2048 + jcol]
              + ghhp[393216 + (size_t)bb * 2048 + jcol];
    float wv = wahp[bb * 512 + tid] + wahp[32768 + bb * 512 + tid]
             + wahp[65536 + bb * 512 + tid] + wahp[98304 + bb * 512 + tid];
    const float cload = c_cur[bb * 512 + qq * 128 + (tid & 127)];

    // per-lane a-slice constants (contiguous 8 a's per lane)
    const int a0 = lane * 8;
    float aw8[8];
    #pragma unroll
    for (int k = 0; k < 8; ++k) aw8[k] = A_w[a0 + k];

    // fW fragment prefetch: thread = (ngf fast, colgroup)
    const int ngf = tid & 7, r = tid >> 3;
    const int gf = r >> 4, oc = r & 15;
    const int jb = gf * 512 + qq * 128 + oc * 8;
    const u16* fb = fW16 + (size_t)bb * NN * 2048 + jb;
    s16x8 pf[7];
    #pragma unroll
    for (int i = 0; i < 7; ++i) {
        const int n = ngf + 8 * i;
        if (n < NN) pf[i] = *(const s16x8*)(fb + (size_t)n * 2048);
        else        pf[i] = (s16x8){0, 0, 0, 0, 0, 0, 0, 0};
    }

    ghl[tid] = ghv;
    wah_l[tid] = wv;
    __syncthreads();

    float wh8[8];
    #pragma unroll
    for (int k = 0; k < 8; ++k) wh8[k] = wah_l[a0 + k];

    // ---- scores: 7 rows per wave, coalesced 16B/lane loads ----
    const u16* ub = uhs16 + (size_t)(bb * NN) * 512 + a0;
    #pragma unroll
    for (int i = 0; i < 7; ++i) {
        const int n = w + 8 * i;
        const int nc = (n < NN) ? n : 0;
        const s16x8 uv = *(const s16x8*)(ub + (size_t)nc * 512);
        float acc = 0.f;
        #pragma unroll
        for (int k = 0; k < 8; ++k)
            acc += aw8[k] * fast_tanh(bf2f((u16)uv[k]) + wh8[k]);
        #pragma unroll
        for (int m = 32; m; m >>= 1) acc += __shfl_xor(acc, m, 64);
        if (lane == 0 && n < NN) red[n] = acc + A_b[0];
    }
    __syncthreads();

    // ---- softmax (wave 0) ----
    if (tid < 64) {
        const float sc = (tid < NN) ? red[tid] : -1e30f;
        float mx = sc;
        #pragma unroll
        for (int m = 32; m; m >>= 1) mx = fmaxf(mx, __shfl_xor(mx, m, 64));
        float e = (tid < NN) ? __expf(sc - mx) : 0.f;
        float sum = e;
        #pragma unroll
        for (int m = 32; m; m >>= 1) sum += __shfl_xor(sum, m, 64);
        const float av = e / sum;
        al[tid] = av;
        if (qq == 0 && tid < NN)
            alphas[(size_t)bb * (TT * NN) + (size_t)s * NN + tid] = av;
    }
    __syncthreads();

    // ---- contraction from prefetched registers; 8-lane shuffle reduce ----
    float a8[8] = {0.f, 0.f, 0.f, 0.f, 0.f, 0.f, 0.f, 0.f};
    #pragma unroll
    for (int i = 0; i < 7; ++i) {
        const int n = ngf + 8 * i;          // al[n>=49] == 0
        const float av = al[n];
        #pragma unroll
        for (int k = 0; k < 8; ++k)
            a8[k] += av * bf2f((u16)pf[i][k]);
    }
    #pragma unroll
    for (int m = 1; m < 8; m <<= 1)
        #pragma unroll
        for (int k = 0; k < 8; ++k)
            a8[k] += __shfl_xor(a8[k], m, 64);
    if (ngf == 0) {
        const int base = gf * 128 + oc * 8;
        #pragma unroll
        for (int k = 0; k < 8; ++k)
            gl[base + k] = a8[k] + ghl[base + k];
    }
    __syncthreads();

    // ---- pointwise LSTM ----
    if (tid < 128) {
        const int dd = qq * 128 + tid;
        const float ig = sigmoidf(gl[tid]);
        const float fg = sigmoidf(gl[128 + tid]);
        const float gg = fast_tanh(gl[256 + tid]);
        const float og = sigmoidf(gl[384 + tid]);
        const float cv = fg * cload + ig * gg;
        const float hv = og * fast_tanh(cv);
        c_cur[bb * 512 + dd] = cv;
        h_cur[bb * 512 + dd] = hv;
        short hh, hl;
        split_bf16(hv, hh, hl);
        Hall_h[(size_t)(s * 64 + bb) * 512 + dd] = (u16)hh;
        Hall_l[(size_t)(s * 64 + bb) * 512 + dd] = (u16)hl;
    }
}

// ---------------------------------------------------------------------------
extern "C" void kernel_launch(void* const* d_in, const int* in_sizes, int n_in,
                              void* d_out, int out_size, void* d_ws, size_t ws_size,
                              hipStream_t stream)
{
    const float* features = (const float*)d_in[0];
    const int*   captions = (const int*)d_in[1];
    const float* emb      = (const float*)d_in[2];
    const float* U_w      = (const float*)d_in[3];
    const float* U_b      = (const float*)d_in[4];
    const float* W_w      = (const float*)d_in[5];
    const float* W_b      = (const float*)d_in[6];
    const float* A_w      = (const float*)d_in[7];
    const float* A_b      = (const float*)d_in[8];
    const float* iH_w     = (const float*)d_in[9];
    const float* iH_b     = (const float*)d_in[10];
    const float* iC_w     = (const float*)d_in[11];
    const float* iC_b     = (const float*)d_in[12];
    const float* ih_w     = (const float*)d_in[13];
    const float* ih_b     = (const float*)d_in[14];
    const float* hh_w     = (const float*)d_in[15];
    const float* hh_b     = (const float*)d_in[16];
    const float* fcn_w    = (const float*)d_in[17];
    const float* fcn_b    = (const float*)d_in[18];

    float* out    = (float*)d_out;
    float* alphas = out + (size_t)B * TT * VOC;

    float* ws     = (float*)d_ws;
    u16*  fW16    = (u16*)ws;                      // 6,422,528 u16 = 3,211,264 f
    u16*  uhs16   = (u16*)(ws + 3211264);          // 1,605,632 u16 =   802,816 f
    float* pre_x  = ws + 4014080;                  // 3,932,160 f
    u16*  Hall_h  = (u16*)(ws + 7946240);          //   491,520 f
    u16*  Hall_l  = (u16*)(ws + 8437760);          //   491,520 f
    float* mean_f = ws + 8929280;                  //   131,072
    float* h_cur  = ws + 9060352;                  //    32,768
    float* c_cur  = ws + 9093120;                  //    32,768
    float* wahp   = ws + 9125888;                  //   131,072 (4*64*512)
    float* ghhp   = ws + 9256960;                  //   524,288 (4*64*2048)
    float* embeds = ws + 9781248;                  //   576,000
    float* bias2  = ws + 10357248;                 //     2,048
    u16*  fhi     = (u16*)(ws + 10359296);         // 6,422,528 u16 = 3,211,264 f
    u16*  flo     = (u16*)(ws + 13570560);         // 3,211,264 f  (end 16,781,824 f = 67.1 MB)
    // aliases (dead producers):
    float* pbuf   = ws;                            // init partials (over fW16, dead before mfma_cat)
    u16*  fcnw_h  = fhi;                           // fcn_w split (after recurrence; fhi dead)
    u16*  fcnw_l  = flo;

    // init hidden state
    k_mean<<<64, 256, 0, stream>>>(features, mean_f);
    k_init_partial<<<dim3(16, 16), 256, 0, stream>>>(mean_f, iH_w, iC_w, pbuf);
    k_init_reduce<<<256, 256, 0, stream>>>(pbuf, iH_b, iC_b, h_cur, c_cur);

    // hoisted precomputes
    k_embed<<<1920, 256, 0, stream>>>(captions, emb, embeds);
    k_bias2<<<8, 256, 0, stream>>>(ih_b, hh_b, bias2);
    // features -> bf16 hi/lo (pre-split A for mfma_cat)
    k_split<<<6272, 256, 0, stream>>>(features, fhi, flo, B * NN * ENC);
    // combined u_hs+fW GEMM: [3136 x 2560] over K=2048
    mfma_cat<<<dim3(20, 25), 512, 0, stream>>>(fhi, flo, U_w, U_b, ih_w, uhs16, fW16, B * NN);
    // pre_x (f32) = embeds @ ih_w[:, :300]^T + bias2    [1920, 2048]
    mfma_nt<<<dim3(16, 15), 512, 0, stream>>>(embeds, EMB, ih_w, 2348, bias2, pre_x, 2048, TT * B, 2048, EMB, 0);

    // recurrence
    k_hw4<<<dim3(40, 4), 256, 0, stream>>>(h_cur, W_w, W_b, hh_w, wahp, ghhp);
    for (int s = 0; s < TT; ++s) {
        k_fused4<<<dim3(64, 4), 512, 0, stream>>>(uhs16, A_w, A_b, wahp, ghhp, pre_x, fW16,
                                                  h_cur, c_cur, Hall_h, Hall_l, alphas, s);
        if (s < TT - 1)
            k_hw4<<<dim3(40, 4), 256, 0, stream>>>(h_cur, W_w, W_b, hh_w, wahp, ghhp);
    }

    // output projection on pre-split bf16
    k_split<<<5000, 256, 0, stream>>>(fcn_w, fcnw_h, fcnw_l, VOC * DEC);
    mfma_pre<<<dim3(79, 15), 512, 0, stream>>>(Hall_h, Hall_l, fcnw_h, fcnw_l, fcn_b,
                                               out, TT * B, VOC);
}